// Round 17
// baseline (150.823 us; speedup 1.0000x reference)
//
#include <hip/hip_runtime.h>
#include <hip/hip_bf16.h>

// B=4 S=1024 D=1024 H=16 DH=64 -> flat M=4096, attention raw view [64][1024][64]

using u16 = unsigned short;
using u32 = unsigned int;
typedef __attribute__((ext_vector_type(8)))  short bf16x8;
typedef __attribute__((ext_vector_type(4)))  float f32x4;
typedef __attribute__((ext_vector_type(16))) float f32x16;
typedef __attribute__((ext_vector_type(4)))  u16  u16x4;
typedef __attribute__((ext_vector_type(8)))  u16  u16x8;

#define AS1C(p) ((const __attribute__((address_space(1))) void*)(p))
#define AS3(p)  ((__attribute__((address_space(3))) void*)(p))

__device__ __forceinline__ u16 f2bf(float f) {
  union { float f; unsigned u; } v; v.f = f;
  unsigned u = v.u;
  return (u16)((u + 0x7fffu + ((u >> 16) & 1u)) >> 16);  // RNE
}

// one-instruction pack: {lo16 = bf16(a), hi16 = bf16(b)}  (gfx950 v_cvt_pk_bf16_f32, RNE)
__device__ __forceinline__ u32 pk_bf16(float a, float b) {
  u32 r;
  asm("v_cvt_pk_bf16_f32 %0, %1, %2" : "=v"(r) : "v"(a), "v"(b));
  return r;
}
// raw hardware exp2 (v_exp_f32 IS 2^x) — log2e folded into the Q scale upstream
__device__ __forceinline__ float exp2fast(float x) {
  float r;
  asm("v_exp_f32 %0, %1" : "=v"(r) : "v"(x));
  return r;
}
__device__ __forceinline__ float bf2f(u16 b) {
  union { u32 u; float f; } v; v.u = ((u32)b) << 16; return v.f;
}

__device__ __forceinline__ f32x4 mfma16(bf16x8 a, bf16x8 b, f32x4 c) {
  return __builtin_amdgcn_mfma_f32_16x16x32_bf16(a, b, c, 0, 0, 0);
}
__device__ __forceinline__ f32x16 mfma32(bf16x8 a, bf16x8 b, f32x16 c) {
  return __builtin_amdgcn_mfma_f32_32x32x16_bf16(a, b, c, 0, 0, 0);
}

// ---------------- prep: fp32->bf16 for x and W's, concat biases ----------------
__global__ __launch_bounds__(256) void prep_kernel(
    const float* __restrict__ x,
    const float* __restrict__ wq, const float* __restrict__ wk,
    const float* __restrict__ wv, const float* __restrict__ wo,
    const float* __restrict__ bq, const float* __restrict__ bk, const float* __restrict__ bv,
    u16* __restrict__ xb, u16* __restrict__ wb, float* __restrict__ bc)
{
  int ch = blockIdx.x * 256 + threadIdx.x;
  if (ch < 2097152) {
    const float* src; u16* dst;
    if (ch < 1048576) { src = x + ch * 4; dst = xb + ch * 4; }
    else {
      int c2 = ch - 1048576;
      int wsel = c2 >> 18;
      int off  = c2 & 262143;
      const float* wsrc[4] = { wq, wk, wv, wo };
      src = wsrc[wsel] + off * 4;
      dst = wb + wsel * 1048576 + off * 4;
    }
    f32x4 v = *(const f32x4*)src;
    union { u32 u[2]; u16x4 v4; } o;
    o.u[0] = pk_bf16(v[0], v[1]);
    o.u[1] = pk_bf16(v[2], v[3]);
    *(u16x4*)dst = o.v4;
  } else {
    int c3 = ch - 2097152;            // < 768
    int bsel = c3 >> 8, off = c3 & 255;
    const float* bsrc[3] = { bq, bk, bv };
    f32x4 v = *(const f32x4*)(bsrc[bsel] + off * 4);
    *(f32x4*)(bc + bsel * 1024 + off * 4) = v;
  }
}

// ---------------- QKV GEMM: 128x128, BK=32, 4 waves, 3-buf counted vmcnt + setprio ----------------
// r11-proven optimum (57-62us). Per K-step: vmcnt(4) -> s_barrier -> STAGE(t+2) -> COMPUTE(t).
// 48KB LDS -> 3 blocks/CU (12 waves/CU). Design-space sweep (r2..r13): 2-phase drain 63.5,
// 4-buf/2blk 96.5, 8-phase-256^2 87, 8-wave 80.5, no-setprio 105 -> THIS config wins:
//  - s_setprio(1) around MFMA cluster: ESSENTIAL (r9 A/B: removing = 59.5->105.5us)
//  - 16 MFMA/wave/step cluster length: ESSENTIAL (r12: halving = 61->80.5us)
//  - block map keeps all 8 writers of each V^T 128B line on one XCD (r5: else 3x write amp)
// Q scale = 0.125*log2(e) -> attention softmax runs in exp2 domain.
__global__ __launch_bounds__(256) void gemm_qkv(
    const u16* __restrict__ A, const u16* __restrict__ Bw,
    const float* __restrict__ bias, u16* __restrict__ outb)
{
  __shared__ u16 As[3][4096];
  __shared__ u16 Bs[3][4096];

  const int K = 1024;
  int tid = threadIdx.x, w = tid >> 6, lane = tid & 63;
  int g = lane >> 4, lr = lane & 15;
  int wr = w >> 1, wcn = w & 1;

  int bid = blockIdx.x;
  int bm = (bid & 7) + 8 * ((bid >> 3) & 3);
  int bn = bid >> 5;

  int ch0 = tid, ch1 = tid + 256;
  auto srcoff = [&](int ch) -> size_t {
    int r = ch >> 2, pc = ch & 3;
    int gc = pc ^ ((r >> 2) & 3);        // source pre-swizzle (involution)
    return (size_t)r * K + gc * 8;
  };
  const u16* aS0 = A  + (size_t)(bm * 128) * K + srcoff(ch0);
  const u16* aS1 = A  + (size_t)(bm * 128) * K + srcoff(ch1);
  const u16* bS0 = Bw + (size_t)(bn * 128) * K + srcoff(ch0);
  const u16* bS1 = Bw + (size_t)(bn * 128) * K + srcoff(ch1);
  int lo0 = ch0 * 8, lo1 = ch1 * 8;

  auto STAGE = [&](int buf, int kt) {
    __builtin_amdgcn_global_load_lds(AS1C(aS0 + kt * 32), AS3(&As[buf][lo0]), 16, 0, 0);
    __builtin_amdgcn_global_load_lds(AS1C(aS1 + kt * 32), AS3(&As[buf][lo1]), 16, 0, 0);
    __builtin_amdgcn_global_load_lds(AS1C(bS0 + kt * 32), AS3(&Bs[buf][lo0]), 16, 0, 0);
    __builtin_amdgcn_global_load_lds(AS1C(bS1 + kt * 32), AS3(&Bs[buf][lo1]), 16, 0, 0);
  };

  f32x4 acc[4][4] = {};
  int pc8 = (g ^ ((lr >> 2) & 3)) * 8;   // swizzled read chunk

  auto COMPUTE = [&](int buf) {
    bf16x8 af[4], bfr[4];
#pragma unroll
    for (int m = 0; m < 4; ++m)
      af[m] = *(const bf16x8*)&As[buf][(wr * 64 + m * 16 + lr) * 32 + pc8];
#pragma unroll
    for (int n = 0; n < 4; ++n)
      bfr[n] = *(const bf16x8*)&Bs[buf][(wcn * 64 + n * 16 + lr) * 32 + pc8];
    __builtin_amdgcn_s_setprio(1);
#pragma unroll
    for (int m = 0; m < 4; ++m)
#pragma unroll
      for (int n = 0; n < 4; ++n)
        acc[m][n] = mfma16(af[m], bfr[n], acc[m][n]);
    __builtin_amdgcn_s_setprio(0);
  };

  STAGE(0, 0); STAGE(1, 1);

  int sb = 2, cb = 0;
  for (int t = 0; t < 31; ++t) {
    asm volatile("s_waitcnt vmcnt(4)" ::: "memory");  // tile t landed; t+1 in flight
    __builtin_amdgcn_s_barrier();
    asm volatile("" ::: "memory");
    if (t < 30) {
      STAGE(sb, t + 2);
      if (++sb == 3) sb = 0;
    }
    COMPUTE(cb);
    if (++cb == 3) cb = 0;
  }
  asm volatile("s_waitcnt vmcnt(0)" ::: "memory");
  __builtin_amdgcn_s_barrier();
  asm volatile("" ::: "memory");
  COMPUTE(cb);

  // epilogue: D layout col=lane&15, row=(lane>>4)*4+i
#pragma unroll
  for (int m = 0; m < 4; ++m) {
    int row0 = bm * 128 + wr * 64 + m * 16 + 4 * g;
#pragma unroll
    for (int n = 0; n < 4; ++n) {
      int col = bn * 128 + wcn * 64 + n * 16 + lr;
#pragma unroll
      for (int i = 0; i < 4; ++i) {
        float v = acc[m][n][i] + bias[col];
        int r = row0 + i;
        if (col < 1024) {
          outb[(size_t)r * 1024 + col] = f2bf(v * 0.18033688f);           // Q * (1/8)*log2(e)
        } else if (col < 2048) {
          outb[4194304 + (size_t)r * 1024 + (col - 1024)] = f2bf(v);     // K
        } else {
          int c = col - 2048;
          // V^T[bh=r>>6][dh=c&63][k=(r&63)*16+(c>>6)]
          outb[8388608 + (size_t)(r >> 6) * 65536 + (size_t)(c & 63) * 1024
               + (r & 63) * 16 + (c >> 6)] = f2bf(v);
        }
      }
    }
  }
}

// ---------------- out-proj GEMM: 64x128 tile, BK=32, 4 waves, 3-buf counted + setprio ----------------
// Writes proj = ctx*Wo^T + bo as bf16 ONLY (8MB); residual-add lives in ln_kernel (r14: -3us).
__global__ __launch_bounds__(256) void gemm_op(
    const u16* __restrict__ A, const u16* __restrict__ Bw,
    const float* __restrict__ bias, u16* __restrict__ outp)
{
  __shared__ u16 As[3][2048];    // [64][32] per buffer
  __shared__ u16 Bs[3][4096];    // [128][32]

  const int K = 1024;
  int tid = threadIdx.x, w = tid >> 6, lane = tid & 63;
  int g = lane >> 4, lr = lane & 15;
  int wr = w >> 1, wcn = w & 1;
  int bid = blockIdx.x;
  int bm = bid & 63, bn = bid >> 6;      // grid 512 = 64 x 8

  auto srcoff = [&](int ch) -> size_t {
    int r = ch >> 2, pc = ch & 3;
    int gc = pc ^ ((r >> 2) & 3);
    return (size_t)r * K + gc * 8;
  };
  const u16* aS0 = A  + (size_t)(bm * 64)  * K + srcoff(tid);
  const u16* bS0 = Bw + (size_t)(bn * 128) * K + srcoff(tid);
  const u16* bS1 = Bw + (size_t)(bn * 128) * K + srcoff(tid + 256);

  auto STAGE = [&](int buf, int kt) {
    __builtin_amdgcn_global_load_lds(AS1C(aS0 + kt * 32), AS3(&As[buf][tid * 8]),        16, 0, 0);
    __builtin_amdgcn_global_load_lds(AS1C(bS0 + kt * 32), AS3(&Bs[buf][tid * 8]),        16, 0, 0);
    __builtin_amdgcn_global_load_lds(AS1C(bS1 + kt * 32), AS3(&Bs[buf][2048 + tid * 8]), 16, 0, 0);
  };

  f32x4 acc[2][4] = {};
  int pc8 = (g ^ ((lr >> 2) & 3)) * 8;

  auto COMPUTE = [&](int buf) {
    bf16x8 af[2], bfr[4];
#pragma unroll
    for (int m = 0; m < 2; ++m)
      af[m] = *(const bf16x8*)&As[buf][(wr * 32 + m * 16 + lr) * 32 + pc8];
#pragma unroll
    for (int n = 0; n < 4; ++n)
      bfr[n] = *(const bf16x8*)&Bs[buf][(wcn * 64 + n * 16 + lr) * 32 + pc8];
    __builtin_amdgcn_s_setprio(1);
#pragma unroll
    for (int m = 0; m < 2; ++m)
#pragma unroll
      for (int n = 0; n < 4; ++n)
        acc[m][n] = mfma16(af[m], bfr[n], acc[m][n]);
    __builtin_amdgcn_s_setprio(0);
  };

  STAGE(0, 0); STAGE(1, 1);

  int sb = 2, cb = 0;
  for (int t = 0; t < 31; ++t) {
    asm volatile("s_waitcnt vmcnt(3)" ::: "memory");
    __builtin_amdgcn_s_barrier();
    asm volatile("" ::: "memory");
    if (t < 30) {
      STAGE(sb, t + 2);
      if (++sb == 3) sb = 0;
    }
    COMPUTE(cb);
    if (++cb == 3) cb = 0;
  }
  asm volatile("s_waitcnt vmcnt(0)" ::: "memory");
  __builtin_amdgcn_s_barrier();
  asm volatile("" ::: "memory");
  COMPUTE(cb);

#pragma unroll
  for (int m = 0; m < 2; ++m) {
    int row0 = bm * 64 + wr * 32 + m * 16 + 4 * g;
#pragma unroll
    for (int n = 0; n < 4; ++n) {
      int col = bn * 128 + wcn * 64 + n * 16 + lr;
#pragma unroll
      for (int i = 0; i < 4; ++i)
        outp[(size_t)(row0 + i) * 1024 + col] = f2bf(acc[m][n][i] + bias[col]);
    }
  }
}

// ---------------- flash attention, 32x32 swapped-operand, NO LDS (L1/L2-direct) ----------------
// r15: K/V are L1/L2-resident (per head 256KB; bh=blk&63 pins a head's 8 blocks to one XCD;
// a block's 4 waves read the SAME 16KB tile -> L1 serves 3 of 4). LDS staging + 32 barriers +
// counted vmcnt were re-buying cached data (Common-mistake #7 / m169). Now: MFMA operands load
// straight from global; waves fully independent (zero barriers, zero LDS). K double-buffered
// in registers (static A/B sets via 2-unrolled loop, rule #20-safe); V issued right after QK^T,
// latency hides under softmax. Math byte-identical to r14 (refcheck'd absmax 0.03125):
//   S^T = mfma32(K,Q), exp2-domain softmax (Q pre-scaled 0.125*log2e), defer-max THR=11,
//   cvt_pk pack, one hi/lo exchange for the PV B-frag, O^T = mfma32(V^T, P).
__global__ __launch_bounds__(256) void attn_kernel(
    const u16* __restrict__ Qb, const u16* __restrict__ Kb,
    const u16* __restrict__ Vtb, u16* __restrict__ Ob)
{
  int blk = blockIdx.x;
  int bh = blk & 63, qt = blk >> 6;          // head h on XCD h%8 -> K/V L2-resident
  int tid = threadIdx.x, wid = tid >> 6, lane = tid & 63;
  int l31 = lane & 31, hi = lane >> 5;

  const u16* Qp = Qb  + (size_t)bh * 65536;
  const u16* Kp = Kb  + (size_t)bh * 65536;
  const u16* Vp = Vtb + (size_t)bh * 65536;

  int q = qt * 128 + wid * 32 + l31;

  // Q as B-operand: lane holds Q[q][s*16+hi*8 .. +8] per 16-k step s
  bf16x8 qf[4];
#pragma unroll
  for (int s = 0; s < 4; ++s)
    qf[s] = *(const bf16x8*)&Qp[(size_t)q * 64 + s * 16 + hi * 8];

  f32x16 oacc[2] = {};
  float mrow = -3e38f, lrow = 0.f;

  // fragment bases (u16 units):
  //   K frag (tile kt, ks, s): Kp[(kt*64 + ks*32 + l31)*64 + s*16 + hi*8]
  //   V frag (tile kt, dt, s): Vp[(dt*32 + l31)*1024 + kt*64 + s*16 + hi*8]
  const u16* kbase = Kp + (size_t)l31 * 64 + hi * 8;
  const u16* vbase = Vp + (size_t)l31 * 1024 + hi * 8;

  auto LOADK = [&](bf16x8 (&kf)[2][4], int kt) {
#pragma unroll
    for (int ks = 0; ks < 2; ++ks)
#pragma unroll
      for (int s = 0; s < 4; ++s)
        kf[ks][s] = *(const bf16x8*)&kbase[kt * 4096 + ks * 2048 + s * 16];
  };

  auto BODY = [&](bf16x8 (&cur)[2][4], bf16x8 (&nxt)[2][4], int kt) {
    // --- S^T = K Q^T (log2-domain scores)
    f32x16 s2[2];
#pragma unroll
    for (int ks = 0; ks < 2; ++ks) {
      f32x16 z = {};
      __builtin_amdgcn_s_setprio(1);
#pragma unroll
      for (int s = 0; s < 4; ++s)
        z = mfma32(cur[ks][s], qf[s], z);
      __builtin_amdgcn_s_setprio(0);
      s2[ks] = z;
    }

    // --- prefetch next tile's K; issue this tile's V (consumed after softmax)
    if (kt + 1 < 16) LOADK(nxt, kt + 1);
    bf16x8 vf[2][4];
#pragma unroll
    for (int dt = 0; dt < 2; ++dt)
#pragma unroll
      for (int s = 0; s < 4; ++s)
        vf[dt][s] = *(const bf16x8*)&vbase[(size_t)dt * 32768 + kt * 64 + s * 16];

    // --- online softmax, in-register (lane owns row q), defer-max THR=11 (log2)
    float tv[16];
#pragma unroll
    for (int r = 0; r < 16; ++r) tv[r] = fmaxf(s2[0][r], s2[1][r]);
#pragma unroll
    for (int st = 8; st > 0; st >>= 1)
#pragma unroll
      for (int r = 0; r < st; ++r) tv[r] = fmaxf(tv[r], tv[r + st]);
    float tm = fmaxf(tv[0], __shfl_xor(tv[0], 32));

    bool nores = __all(tm - mrow <= 11.0f);
    float mn, corr;
    if (nores) { mn = mrow; corr = 1.f; }
    else       { mn = fmaxf(mrow, tm); corr = exp2fast(mrow - mn); }

    float sv[16];
#pragma unroll
    for (int r = 0; r < 16; ++r) {
      s2[0][r] = exp2fast(s2[0][r] - mn);
      s2[1][r] = exp2fast(s2[1][r] - mn);
      sv[r] = s2[0][r] + s2[1][r];
    }
#pragma unroll
    for (int st = 8; st > 0; st >>= 1)
#pragma unroll
      for (int r = 0; r < st; ++r) sv[r] += sv[r + st];
    float rs = sv[0] + __shfl_xor(sv[0], 32);

    if (nores) {
      lrow += rs;
    } else {
#pragma unroll
      for (int dt = 0; dt < 2; ++dt)
#pragma unroll
        for (int r = 0; r < 16; ++r) oacc[dt][r] *= corr;
      lrow = lrow * corr + rs;
      mrow = mn;
    }

    // --- pack P to bf16 pairs via cvt_pk: w[ks][r1][p] = {k=4hi+8r1+2p, +1}
    u32 wpk[2][4][2];
#pragma unroll
    for (int ks = 0; ks < 2; ++ks)
#pragma unroll
      for (int r1 = 0; r1 < 4; ++r1)
#pragma unroll
        for (int p = 0; p < 2; ++p)
          wpk[ks][r1][p] = pk_bf16(s2[ks][4 * r1 + 2 * p], s2[ks][4 * r1 + 2 * p + 1]);

    // --- PV: 4 k-steps of 16; build pb via one hi/lo exchange (r8-verified)
#pragma unroll
    for (int s = 0; s < 4; ++s) {
      int ks = s >> 1, t = s & 1;
      u32 a0 = wpk[ks][2 * t][0],     a1 = wpk[ks][2 * t][1];
      u32 b0 = wpk[ks][2 * t + 1][0], b1 = wpk[ks][2 * t + 1][1];
      u32 sa0 = (u32)__shfl_xor((int)a0, 32), sa1 = (u32)__shfl_xor((int)a1, 32);
      u32 sb0 = (u32)__shfl_xor((int)b0, 32), sb1 = (u32)__shfl_xor((int)b1, 32);
      union { u32 u[4]; bf16x8 v; } pb;
      pb.u[0] = hi ? sb0 : a0;
      pb.u[1] = hi ? sb1 : a1;
      pb.u[2] = hi ? b0 : sa0;
      pb.u[3] = hi ? b1 : sa1;
      __builtin_amdgcn_s_setprio(1);
#pragma unroll
      for (int dt = 0; dt < 2; ++dt)
        oacc[dt] = mfma32(vf[dt][s], pb.v, oacc[dt]);
      __builtin_amdgcn_s_setprio(0);
    }
  };

  bf16x8 kfA[2][4], kfB[2][4];
  LOADK(kfA, 0);
  for (int t2 = 0; t2 < 8; ++t2) {
    BODY(kfA, kfB, 2 * t2);
    BODY(kfB, kfA, 2 * t2 + 1);
  }

  // epilogue: ctx[q][d] = O^T[d][q] / lrow ; d_local(reg r) = (r&3)+8*(r>>2)+4hi
  float inv = 1.f / lrow;
  u16* Op = Ob + (size_t)bh * 65536 + (size_t)q * 64;
#pragma unroll
  for (int dt = 0; dt < 2; ++dt)
#pragma unroll
    for (int rq = 0; rq < 4; ++rq) {
      int d0 = dt * 32 + 8 * rq + 4 * hi;
      union { u32 u[2]; u16x4 v; } o4;
      o4.u[0] = pk_bf16(oacc[dt][4 * rq + 0] * inv, oacc[dt][4 * rq + 1] * inv);
      o4.u[1] = pk_bf16(oacc[dt][4 * rq + 2] * inv, oacc[dt][4 * rq + 3] * inv);
      *(u16x4*)&Op[d0] = o4.v;
    }
}

// ---------------- LayerNorm: out = LN(x + proj), rows of [4096][1024] ----------------
// Residual add fused here (r14): reads proj bf16 (8MB) + x f32 (16MB), writes out f32 (16MB).
__global__ __launch_bounds__(256) void ln_kernel(
    const float* __restrict__ xres, const u16* __restrict__ proj,
    float* __restrict__ out,
    const float* __restrict__ gamma, const float* __restrict__ beta)
{
  int row = blockIdx.x, tid = threadIdx.x;
  int lane = tid & 63, wid = tid >> 6;
  f32x4 xv = *(const f32x4*)&xres[(size_t)row * 1024 + tid * 4];
  u16x4 pv = *(const u16x4*)&proj[(size_t)row * 1024 + tid * 4];
  f32x4 v;
#pragma unroll
  for (int j = 0; j < 4; ++j) v[j] = xv[j] + bf2f(pv[j]);
  float s = v[0] + v[1] + v[2] + v[3];
  float q = v[0] * v[0] + v[1] * v[1] + v[2] * v[2] + v[3] * v[3];
#pragma unroll
  for (int ms = 1; ms < 64; ms <<= 1) { s += __shfl_xor(s, ms); q += __shfl_xor(q, ms); }
  __shared__ float red[8];
  if (lane == 0) { red[wid] = s; red[wid + 4] = q; }
  __syncthreads();
  s = red[0] + red[1] + red[2] + red[3];
  q = red[4] + red[5] + red[6] + red[7];
  float mu = s * (1.f / 1024.f);
  float var = q * (1.f / 1024.f) - mu * mu;
  float inv = rsqrtf(var + 1e-5f);
  f32x4 g4 = *(const f32x4*)&gamma[tid * 4];
  f32x4 b4 = *(const f32x4*)&beta[tid * 4];
  f32x4 o;
#pragma unroll
  for (int j = 0; j < 4; ++j) o[j] = (v[j] - mu) * inv * g4[j] + b4[j];
  *(f32x4*)&out[(size_t)row * 1024 + tid * 4] = o;
}

// ---------------- launch ----------------
extern "C" void kernel_launch(void* const* d_in, const int* in_sizes, int n_in,
                              void* d_out, int out_size, void* d_ws, size_t ws_size,
                              hipStream_t stream) {
  const float* x     = (const float*)d_in[0];
  const float* Wq    = (const float*)d_in[1];
  const float* bq    = (const float*)d_in[2];
  const float* Wk    = (const float*)d_in[3];
  const float* bk    = (const float*)d_in[4];
  const float* Wv    = (const float*)d_in[5];
  const float* bv    = (const float*)d_in[6];
  const float* Wo    = (const float*)d_in[7];
  const float* bo    = (const float*)d_in[8];
  const float* gamma = (const float*)d_in[9];
  const float* beta  = (const float*)d_in[10];
  float* out = (float*)d_out;

  char* ws = (char*)d_ws;
  u16*   xb  = (u16*)ws;                                   // 8MB  [4096][1024] bf16 (reused as ctx)
  u16*   wb  = (u16*)(ws + (8u << 20));                    // 8MB  Wq|Wk|Wv|Wo bf16
  float* bc  = (float*)(ws + (16u << 20));                 // 12KB bq|bk|bv
  u16*   qkv = (u16*)(ws + (16u << 20) + 16384);           // 24MB Q | K | V^T bf16
  u16*   ctx = xb;                                         // overlay: xb dead after QKV GEMM
  u16*   proj = qkv;                                       // overlay: Q dead after attention

  prep_kernel<<<8195, 256, 0, stream>>>(x, Wq, Wk, Wv, Wo, bq, bk, bv, xb, wb, bc);

  // QKV: M=4096 x N=3072 -> grid 768 (bm=(bid&7)+8*((bid>>3)&3), bn=bid>>5)
  gemm_qkv<<<768, 256, 0, stream>>>(xb, wb, bc, qkv);

  // attention: 512 blocks x 256 threads (4 waves x 32 q), 128 q/block, no LDS
  attn_kernel<<<512, 256, 0, stream>>>(qkv, qkv + 4194304, qkv + 8388608, ctx);

  // out-proj: M=4096 x N=1024, 64x128 tiles -> grid 512; writes proj bf16 only
  gemm_op<<<512, 256, 0, stream>>>(ctx, wb + 3 * 1048576, bo, proj);

  // LN with fused residual: out = LN(x + proj)
  ln_kernel<<<4096, 256, 0, stream>>>(x, proj, out, gamma, beta);
}

// Round 18
// 150.238 us; speedup vs baseline: 1.0039x; 1.0039x over previous
//
#include <hip/hip_runtime.h>
#include <hip/hip_bf16.h>

// B=4 S=1024 D=1024 H=16 DH=64 -> flat M=4096, attention raw view [64][1024][64]

using u16 = unsigned short;
using u32 = unsigned int;
typedef __attribute__((ext_vector_type(8)))  short bf16x8;
typedef __attribute__((ext_vector_type(4)))  float f32x4;
typedef __attribute__((ext_vector_type(16))) float f32x16;
typedef __attribute__((ext_vector_type(4)))  u16  u16x4;
typedef __attribute__((ext_vector_type(8)))  u16  u16x8;

#define AS1C(p) ((const __attribute__((address_space(1))) void*)(p))
#define AS3(p)  ((__attribute__((address_space(3))) void*)(p))

__device__ __forceinline__ u16 f2bf(float f) {
  union { float f; unsigned u; } v; v.f = f;
  unsigned u = v.u;
  return (u16)((u + 0x7fffu + ((u >> 16) & 1u)) >> 16);  // RNE
}

// one-instruction pack: {lo16 = bf16(a), hi16 = bf16(b)}  (gfx950 v_cvt_pk_bf16_f32, RNE)
__device__ __forceinline__ u32 pk_bf16(float a, float b) {
  u32 r;
  asm("v_cvt_pk_bf16_f32 %0, %1, %2" : "=v"(r) : "v"(a), "v"(b));
  return r;
}
// raw hardware exp2 (v_exp_f32 IS 2^x) — log2e folded into the Q scale upstream
__device__ __forceinline__ float exp2fast(float x) {
  float r;
  asm("v_exp_f32 %0, %1" : "=v"(r) : "v"(x));
  return r;
}
__device__ __forceinline__ float bf2f(u16 b) {
  union { u32 u; float f; } v; v.u = ((u32)b) << 16; return v.f;
}

__device__ __forceinline__ f32x4 mfma16(bf16x8 a, bf16x8 b, f32x4 c) {
  return __builtin_amdgcn_mfma_f32_16x16x32_bf16(a, b, c, 0, 0, 0);
}
__device__ __forceinline__ f32x16 mfma32(bf16x8 a, bf16x8 b, f32x16 c) {
  return __builtin_amdgcn_mfma_f32_32x32x16_bf16(a, b, c, 0, 0, 0);
}

// ---------------- prep: fp32->bf16 for x and W's, concat biases ----------------
__global__ __launch_bounds__(256) void prep_kernel(
    const float* __restrict__ x,
    const float* __restrict__ wq, const float* __restrict__ wk,
    const float* __restrict__ wv, const float* __restrict__ wo,
    const float* __restrict__ bq, const float* __restrict__ bk, const float* __restrict__ bv,
    u16* __restrict__ xb, u16* __restrict__ wb, float* __restrict__ bc)
{
  int ch = blockIdx.x * 256 + threadIdx.x;
  if (ch < 2097152) {
    const float* src; u16* dst;
    if (ch < 1048576) { src = x + ch * 4; dst = xb + ch * 4; }
    else {
      int c2 = ch - 1048576;
      int wsel = c2 >> 18;
      int off  = c2 & 262143;
      const float* wsrc[4] = { wq, wk, wv, wo };
      src = wsrc[wsel] + off * 4;
      dst = wb + wsel * 1048576 + off * 4;
    }
    f32x4 v = *(const f32x4*)src;
    union { u32 u[2]; u16x4 v4; } o;
    o.u[0] = pk_bf16(v[0], v[1]);
    o.u[1] = pk_bf16(v[2], v[3]);
    *(u16x4*)dst = o.v4;
  } else {
    int c3 = ch - 2097152;            // < 768
    int bsel = c3 >> 8, off = c3 & 255;
    const float* bsrc[3] = { bq, bk, bv };
    f32x4 v = *(const f32x4*)(bsrc[bsel] + off * 4);
    *(f32x4*)(bc + bsel * 1024 + off * 4) = v;
  }
}

// ---------------- QKV GEMM: 128x128, BK=32, 4 waves, 3-buf counted vmcnt + setprio ----------------
// r11-proven optimum (57-62us). Per K-step: vmcnt(4) -> s_barrier -> STAGE(t+2) -> COMPUTE(t).
// 48KB LDS -> 3 blocks/CU (12 waves/CU). Design-space sweep (r2..r13): 2-phase drain 63.5,
// 4-buf/2blk 96.5, 8-phase-256^2 87, 8-wave 80.5, no-setprio 105 -> THIS config wins:
//  - s_setprio(1) around MFMA cluster: ESSENTIAL (r9 A/B: removing = 59.5->105.5us)
//  - 16 MFMA/wave/step cluster length: ESSENTIAL (r12: halving = 61->80.5us)
//  - block map keeps all 8 writers of each V^T 128B line on one XCD (r5: else 3x write amp)
// Q scale = 0.125*log2(e) -> attention softmax runs in exp2 domain.
__global__ __launch_bounds__(256) void gemm_qkv(
    const u16* __restrict__ A, const u16* __restrict__ Bw,
    const float* __restrict__ bias, u16* __restrict__ outb)
{
  __shared__ u16 As[3][4096];
  __shared__ u16 Bs[3][4096];

  const int K = 1024;
  int tid = threadIdx.x, w = tid >> 6, lane = tid & 63;
  int g = lane >> 4, lr = lane & 15;
  int wr = w >> 1, wcn = w & 1;

  int bid = blockIdx.x;
  int bm = (bid & 7) + 8 * ((bid >> 3) & 3);
  int bn = bid >> 5;

  int ch0 = tid, ch1 = tid + 256;
  auto srcoff = [&](int ch) -> size_t {
    int r = ch >> 2, pc = ch & 3;
    int gc = pc ^ ((r >> 2) & 3);        // source pre-swizzle (involution)
    return (size_t)r * K + gc * 8;
  };
  const u16* aS0 = A  + (size_t)(bm * 128) * K + srcoff(ch0);
  const u16* aS1 = A  + (size_t)(bm * 128) * K + srcoff(ch1);
  const u16* bS0 = Bw + (size_t)(bn * 128) * K + srcoff(ch0);
  const u16* bS1 = Bw + (size_t)(bn * 128) * K + srcoff(ch1);
  int lo0 = ch0 * 8, lo1 = ch1 * 8;

  auto STAGE = [&](int buf, int kt) {
    __builtin_amdgcn_global_load_lds(AS1C(aS0 + kt * 32), AS3(&As[buf][lo0]), 16, 0, 0);
    __builtin_amdgcn_global_load_lds(AS1C(aS1 + kt * 32), AS3(&As[buf][lo1]), 16, 0, 0);
    __builtin_amdgcn_global_load_lds(AS1C(bS0 + kt * 32), AS3(&Bs[buf][lo0]), 16, 0, 0);
    __builtin_amdgcn_global_load_lds(AS1C(bS1 + kt * 32), AS3(&Bs[buf][lo1]), 16, 0, 0);
  };

  f32x4 acc[4][4] = {};
  int pc8 = (g ^ ((lr >> 2) & 3)) * 8;   // swizzled read chunk

  auto COMPUTE = [&](int buf) {
    bf16x8 af[4], bfr[4];
#pragma unroll
    for (int m = 0; m < 4; ++m)
      af[m] = *(const bf16x8*)&As[buf][(wr * 64 + m * 16 + lr) * 32 + pc8];
#pragma unroll
    for (int n = 0; n < 4; ++n)
      bfr[n] = *(const bf16x8*)&Bs[buf][(wcn * 64 + n * 16 + lr) * 32 + pc8];
    __builtin_amdgcn_s_setprio(1);
#pragma unroll
    for (int m = 0; m < 4; ++m)
#pragma unroll
      for (int n = 0; n < 4; ++n)
        acc[m][n] = mfma16(af[m], bfr[n], acc[m][n]);
    __builtin_amdgcn_s_setprio(0);
  };

  STAGE(0, 0); STAGE(1, 1);

  int sb = 2, cb = 0;
  for (int t = 0; t < 31; ++t) {
    asm volatile("s_waitcnt vmcnt(4)" ::: "memory");  // tile t landed; t+1 in flight
    __builtin_amdgcn_s_barrier();
    asm volatile("" ::: "memory");
    if (t < 30) {
      STAGE(sb, t + 2);
      if (++sb == 3) sb = 0;
    }
    COMPUTE(cb);
    if (++cb == 3) cb = 0;
  }
  asm volatile("s_waitcnt vmcnt(0)" ::: "memory");
  __builtin_amdgcn_s_barrier();
  asm volatile("" ::: "memory");
  COMPUTE(cb);

  // epilogue: D layout col=lane&15, row=(lane>>4)*4+i
#pragma unroll
  for (int m = 0; m < 4; ++m) {
    int row0 = bm * 128 + wr * 64 + m * 16 + 4 * g;
#pragma unroll
    for (int n = 0; n < 4; ++n) {
      int col = bn * 128 + wcn * 64 + n * 16 + lr;
#pragma unroll
      for (int i = 0; i < 4; ++i) {
        float v = acc[m][n][i] + bias[col];
        int r = row0 + i;
        if (col < 1024) {
          outb[(size_t)r * 1024 + col] = f2bf(v * 0.18033688f);           // Q * (1/8)*log2(e)
        } else if (col < 2048) {
          outb[4194304 + (size_t)r * 1024 + (col - 1024)] = f2bf(v);     // K
        } else {
          int c = col - 2048;
          // V^T[bh=r>>6][dh=c&63][k=(r&63)*16+(c>>6)]
          outb[8388608 + (size_t)(r >> 6) * 65536 + (size_t)(c & 63) * 1024
               + (r & 63) * 16 + (c >> 6)] = f2bf(v);
        }
      }
    }
  }
}

// ---------------- out-proj GEMM: 64x128 tile, BK=32, 4 waves, 3-buf counted + setprio ----------------
// Writes proj = ctx*Wo^T + bo as bf16 ONLY (8MB); residual-add lives in ln_kernel (r14: -3us).
__global__ __launch_bounds__(256) void gemm_op(
    const u16* __restrict__ A, const u16* __restrict__ Bw,
    const float* __restrict__ bias, u16* __restrict__ outp)
{
  __shared__ u16 As[3][2048];    // [64][32] per buffer
  __shared__ u16 Bs[3][4096];    // [128][32]

  const int K = 1024;
  int tid = threadIdx.x, w = tid >> 6, lane = tid & 63;
  int g = lane >> 4, lr = lane & 15;
  int wr = w >> 1, wcn = w & 1;
  int bid = blockIdx.x;
  int bm = bid & 63, bn = bid >> 6;      // grid 512 = 64 x 8

  auto srcoff = [&](int ch) -> size_t {
    int r = ch >> 2, pc = ch & 3;
    int gc = pc ^ ((r >> 2) & 3);
    return (size_t)r * K + gc * 8;
  };
  const u16* aS0 = A  + (size_t)(bm * 64)  * K + srcoff(tid);
  const u16* bS0 = Bw + (size_t)(bn * 128) * K + srcoff(tid);
  const u16* bS1 = Bw + (size_t)(bn * 128) * K + srcoff(tid + 256);

  auto STAGE = [&](int buf, int kt) {
    __builtin_amdgcn_global_load_lds(AS1C(aS0 + kt * 32), AS3(&As[buf][tid * 8]),        16, 0, 0);
    __builtin_amdgcn_global_load_lds(AS1C(bS0 + kt * 32), AS3(&Bs[buf][tid * 8]),        16, 0, 0);
    __builtin_amdgcn_global_load_lds(AS1C(bS1 + kt * 32), AS3(&Bs[buf][2048 + tid * 8]), 16, 0, 0);
  };

  f32x4 acc[2][4] = {};
  int pc8 = (g ^ ((lr >> 2) & 3)) * 8;

  auto COMPUTE = [&](int buf) {
    bf16x8 af[2], bfr[4];
#pragma unroll
    for (int m = 0; m < 2; ++m)
      af[m] = *(const bf16x8*)&As[buf][(wr * 32 + m * 16 + lr) * 32 + pc8];
#pragma unroll
    for (int n = 0; n < 4; ++n)
      bfr[n] = *(const bf16x8*)&Bs[buf][(wcn * 64 + n * 16 + lr) * 32 + pc8];
    __builtin_amdgcn_s_setprio(1);
#pragma unroll
    for (int m = 0; m < 2; ++m)
#pragma unroll
      for (int n = 0; n < 4; ++n)
        acc[m][n] = mfma16(af[m], bfr[n], acc[m][n]);
    __builtin_amdgcn_s_setprio(0);
  };

  STAGE(0, 0); STAGE(1, 1);

  int sb = 2, cb = 0;
  for (int t = 0; t < 31; ++t) {
    asm volatile("s_waitcnt vmcnt(3)" ::: "memory");
    __builtin_amdgcn_s_barrier();
    asm volatile("" ::: "memory");
    if (t < 30) {
      STAGE(sb, t + 2);
      if (++sb == 3) sb = 0;
    }
    COMPUTE(cb);
    if (++cb == 3) cb = 0;
  }
  asm volatile("s_waitcnt vmcnt(0)" ::: "memory");
  __builtin_amdgcn_s_barrier();
  asm volatile("" ::: "memory");
  COMPUTE(cb);

#pragma unroll
  for (int m = 0; m < 2; ++m) {
    int row0 = bm * 64 + wr * 32 + m * 16 + 4 * g;
#pragma unroll
    for (int n = 0; n < 4; ++n) {
      int col = bn * 128 + wcn * 64 + n * 16 + lr;
#pragma unroll
      for (int i = 0; i < 4; ++i)
        outp[(size_t)(row0 + i) * 1024 + col] = f2bf(acc[m][n][i] + bias[col]);
    }
  }
}

// ---------------- flash attention, 32x32 swapped-operand, NO LDS (L1/L2-direct) ----------------
// r15: K/V are L1/L2-resident (per head 256KB; bh=blk&63 pins a head's 8 blocks to one XCD;
// a block's 4 waves read the SAME 16KB tile -> L1 serves 3 of 4). LDS staging + 32 barriers +
// counted vmcnt were re-buying cached data (Common-mistake #7 / m169). Now: MFMA operands load
// straight from global; waves fully independent (zero barriers, zero LDS). K double-buffered
// in registers (static A/B sets via 2-unrolled loop, rule #20-safe); V issued right after QK^T,
// latency hides under softmax. Math byte-identical to r14 (refcheck'd absmax 0.03125):
//   S^T = mfma32(K,Q), exp2-domain softmax (Q pre-scaled 0.125*log2e), defer-max THR=11,
//   cvt_pk pack, one hi/lo exchange for the PV B-frag, O^T = mfma32(V^T, P).
__global__ __launch_bounds__(256) void attn_kernel(
    const u16* __restrict__ Qb, const u16* __restrict__ Kb,
    const u16* __restrict__ Vtb, u16* __restrict__ Ob)
{
  int blk = blockIdx.x;
  int bh = blk & 63, qt = blk >> 6;          // head h on XCD h%8 -> K/V L2-resident
  int tid = threadIdx.x, wid = tid >> 6, lane = tid & 63;
  int l31 = lane & 31, hi = lane >> 5;

  const u16* Qp = Qb  + (size_t)bh * 65536;
  const u16* Kp = Kb  + (size_t)bh * 65536;
  const u16* Vp = Vtb + (size_t)bh * 65536;

  int q = qt * 128 + wid * 32 + l31;

  // Q as B-operand: lane holds Q[q][s*16+hi*8 .. +8] per 16-k step s
  bf16x8 qf[4];
#pragma unroll
  for (int s = 0; s < 4; ++s)
    qf[s] = *(const bf16x8*)&Qp[(size_t)q * 64 + s * 16 + hi * 8];

  f32x16 oacc[2] = {};
  float mrow = -3e38f, lrow = 0.f;

  // fragment bases (u16 units):
  //   K frag (tile kt, ks, s): Kp[(kt*64 + ks*32 + l31)*64 + s*16 + hi*8]
  //   V frag (tile kt, dt, s): Vp[(dt*32 + l31)*1024 + kt*64 + s*16 + hi*8]
  const u16* kbase = Kp + (size_t)l31 * 64 + hi * 8;
  const u16* vbase = Vp + (size_t)l31 * 1024 + hi * 8;

  auto LOADK = [&](bf16x8 (&kf)[2][4], int kt) {
#pragma unroll
    for (int ks = 0; ks < 2; ++ks)
#pragma unroll
      for (int s = 0; s < 4; ++s)
        kf[ks][s] = *(const bf16x8*)&kbase[kt * 4096 + ks * 2048 + s * 16];
  };

  auto BODY = [&](bf16x8 (&cur)[2][4], bf16x8 (&nxt)[2][4], int kt) {
    // --- S^T = K Q^T (log2-domain scores)
    f32x16 s2[2];
#pragma unroll
    for (int ks = 0; ks < 2; ++ks) {
      f32x16 z = {};
      __builtin_amdgcn_s_setprio(1);
#pragma unroll
      for (int s = 0; s < 4; ++s)
        z = mfma32(cur[ks][s], qf[s], z);
      __builtin_amdgcn_s_setprio(0);
      s2[ks] = z;
    }

    // --- prefetch next tile's K; issue this tile's V (consumed after softmax)
    if (kt + 1 < 16) LOADK(nxt, kt + 1);
    bf16x8 vf[2][4];
#pragma unroll
    for (int dt = 0; dt < 2; ++dt)
#pragma unroll
      for (int s = 0; s < 4; ++s)
        vf[dt][s] = *(const bf16x8*)&vbase[(size_t)dt * 32768 + kt * 64 + s * 16];

    // --- online softmax, in-register (lane owns row q), defer-max THR=11 (log2)
    float tv[16];
#pragma unroll
    for (int r = 0; r < 16; ++r) tv[r] = fmaxf(s2[0][r], s2[1][r]);
#pragma unroll
    for (int st = 8; st > 0; st >>= 1)
#pragma unroll
      for (int r = 0; r < st; ++r) tv[r] = fmaxf(tv[r], tv[r + st]);
    float tm = fmaxf(tv[0], __shfl_xor(tv[0], 32));

    bool nores = __all(tm - mrow <= 11.0f);
    float mn, corr;
    if (nores) { mn = mrow; corr = 1.f; }
    else       { mn = fmaxf(mrow, tm); corr = exp2fast(mrow - mn); }

    float sv[16];
#pragma unroll
    for (int r = 0; r < 16; ++r) {
      s2[0][r] = exp2fast(s2[0][r] - mn);
      s2[1][r] = exp2fast(s2[1][r] - mn);
      sv[r] = s2[0][r] + s2[1][r];
    }
#pragma unroll
    for (int st = 8; st > 0; st >>= 1)
#pragma unroll
      for (int r = 0; r < st; ++r) sv[r] += sv[r + st];
    float rs = sv[0] + __shfl_xor(sv[0], 32);

    if (nores) {
      lrow += rs;
    } else {
#pragma unroll
      for (int dt = 0; dt < 2; ++dt)
#pragma unroll
        for (int r = 0; r < 16; ++r) oacc[dt][r] *= corr;
      lrow = lrow * corr + rs;
      mrow = mn;
    }

    // --- pack P to bf16 pairs via cvt_pk: w[ks][r1][p] = {k=4hi+8r1+2p, +1}
    u32 wpk[2][4][2];
#pragma unroll
    for (int ks = 0; ks < 2; ++ks)
#pragma unroll
      for (int r1 = 0; r1 < 4; ++r1)
#pragma unroll
        for (int p = 0; p < 2; ++p)
          wpk[ks][r1][p] = pk_bf16(s2[ks][4 * r1 + 2 * p], s2[ks][4 * r1 + 2 * p + 1]);

    // --- PV: 4 k-steps of 16; build pb via one hi/lo exchange (r8-verified)
#pragma unroll
    for (int s = 0; s < 4; ++s) {
      int ks = s >> 1, t = s & 1;
      u32 a0 = wpk[ks][2 * t][0],     a1 = wpk[ks][2 * t][1];
      u32 b0 = wpk[ks][2 * t + 1][0], b1 = wpk[ks][2 * t + 1][1];
      u32 sa0 = (u32)__shfl_xor((int)a0, 32), sa1 = (u32)__shfl_xor((int)a1, 32);
      u32 sb0 = (u32)__shfl_xor((int)b0, 32), sb1 = (u32)__shfl_xor((int)b1, 32);
      union { u32 u[4]; bf16x8 v; } pb;
      pb.u[0] = hi ? sb0 : a0;
      pb.u[1] = hi ? sb1 : a1;
      pb.u[2] = hi ? b0 : sa0;
      pb.u[3] = hi ? b1 : sa1;
      __builtin_amdgcn_s_setprio(1);
#pragma unroll
      for (int dt = 0; dt < 2; ++dt)
        oacc[dt] = mfma32(vf[dt][s], pb.v, oacc[dt]);
      __builtin_amdgcn_s_setprio(0);
    }
  };

  bf16x8 kfA[2][4], kfB[2][4];
  LOADK(kfA, 0);
  for (int t2 = 0; t2 < 8; ++t2) {
    BODY(kfA, kfB, 2 * t2);
    BODY(kfB, kfA, 2 * t2 + 1);
  }

  // epilogue: ctx[q][d] = O^T[d][q] / lrow ; d_local(reg r) = (r&3)+8*(r>>2)+4hi
  float inv = 1.f / lrow;
  u16* Op = Ob + (size_t)bh * 65536 + (size_t)q * 64;
#pragma unroll
  for (int dt = 0; dt < 2; ++dt)
#pragma unroll
    for (int rq = 0; rq < 4; ++rq) {
      int d0 = dt * 32 + 8 * rq + 4 * hi;
      union { u32 u[2]; u16x4 v; } o4;
      o4.u[0] = pk_bf16(oacc[dt][4 * rq + 0] * inv, oacc[dt][4 * rq + 1] * inv);
      o4.u[1] = pk_bf16(oacc[dt][4 * rq + 2] * inv, oacc[dt][4 * rq + 3] * inv);
      *(u16x4*)&Op[d0] = o4.v;
    }
}

// ---------------- LayerNorm: out = LN(x + proj), rows of [4096][1024] ----------------
// Residual add fused here (r14): reads proj bf16 (8MB) + x f32 (16MB), writes out f32 (16MB).
__global__ __launch_bounds__(256) void ln_kernel(
    const float* __restrict__ xres, const u16* __restrict__ proj,
    float* __restrict__ out,
    const float* __restrict__ gamma, const float* __restrict__ beta)
{
  int row = blockIdx.x, tid = threadIdx.x;
  int lane = tid & 63, wid = tid >> 6;
  f32x4 xv = *(const f32x4*)&xres[(size_t)row * 1024 + tid * 4];
  u16x4 pv = *(const u16x4*)&proj[(size_t)row * 1024 + tid * 4];
  f32x4 v;
#pragma unroll
  for (int j = 0; j < 4; ++j) v[j] = xv[j] + bf2f(pv[j]);
  float s = v[0] + v[1] + v[2] + v[3];
  float q = v[0] * v[0] + v[1] * v[1] + v[2] * v[2] + v[3] * v[3];
#pragma unroll
  for (int ms = 1; ms < 64; ms <<= 1) { s += __shfl_xor(s, ms); q += __shfl_xor(q, ms); }
  __shared__ float red[8];
  if (lane == 0) { red[wid] = s; red[wid + 4] = q; }
  __syncthreads();
  s = red[0] + red[1] + red[2] + red[3];
  q = red[4] + red[5] + red[6] + red[7];
  float mu = s * (1.f / 1024.f);
  float var = q * (1.f / 1024.f) - mu * mu;
  float inv = rsqrtf(var + 1e-5f);
  f32x4 g4 = *(const f32x4*)&gamma[tid * 4];
  f32x4 b4 = *(const f32x4*)&beta[tid * 4];
  f32x4 o;
#pragma unroll
  for (int j = 0; j < 4; ++j) o[j] = (v[j] - mu) * inv * g4[j] + b4[j];
  *(f32x4*)&out[(size_t)row * 1024 + tid * 4] = o;
}

// ---------------- launch ----------------
extern "C" void kernel_launch(void* const* d_in, const int* in_sizes, int n_in,
                              void* d_out, int out_size, void* d_ws, size_t ws_size,
                              hipStream_t stream) {
  const float* x     = (const float*)d_in[0];
  const float* Wq    = (const float*)d_in[1];
  const float* bq    = (const float*)d_in[2];
  const float* Wk    = (const float*)d_in[3];
  const float* bk    = (const float*)d_in[4];
  const float* Wv    = (const float*)d_in[5];
  const float* bv    = (const float*)d_in[6];
  const float* Wo    = (const float*)d_in[7];
  const float* bo    = (const float*)d_in[8];
  const float* gamma = (const float*)d_in[9];
  const float* beta  = (const float*)d_in[10];
  float* out = (float*)d_out;

  char* ws = (char*)d_ws;
  u16*   xb  = (u16*)ws;                                   // 8MB  [4096][1024] bf16 (reused as ctx)
  u16*   wb  = (u16*)(ws + (8u << 20));                    // 8MB  Wq|Wk|Wv|Wo bf16
  float* bc  = (float*)(ws + (16u << 20));                 // 12KB bq|bk|bv
  u16*   qkv = (u16*)(ws + (16u << 20) + 16384);           // 24MB Q | K | V^T bf16
  u16*   ctx = xb;                                         // overlay: xb dead after QKV GEMM
  u16*   proj = qkv;                                       // overlay: Q dead after attention

  prep_kernel<<<8195, 256, 0, stream>>>(x, Wq, Wk, Wv, Wo, bq, bk, bv, xb, wb, bc);

  // QKV: M=4096 x N=3072 -> grid 768 (bm=(bid&7)+8*((bid>>3)&3), bn=bid>>5)
  gemm_qkv<<<768, 256, 0, stream>>>(xb, wb, bc, qkv);

  // attention: 512 blocks x 256 threads (4 waves x 32 q), 128 q/block, no LDS
  attn_kernel<<<512, 256, 0, stream>>>(qkv, qkv + 4194304, qkv + 8388608, ctx);

  // out-proj: M=4096 x N=1024, 64x128 tiles -> grid 512; writes proj bf16 only
  gemm_op<<<512, 256, 0, stream>>>(ctx, wb + 3 * 1048576, bo, proj);

  // LN with fused residual: out = LN(x + proj)
  ln_kernel<<<4096, 256, 0, stream>>>(x, proj, out, gamma, beta);
}

// Round 19
// 149.985 us; speedup vs baseline: 1.0056x; 1.0017x over previous
//
#include <hip/hip_runtime.h>
#include <hip/hip_bf16.h>

// B=4 S=1024 D=1024 H=16 DH=64 -> flat M=4096, attention raw view [64][1024][64]

using u16 = unsigned short;
using u32 = unsigned int;
typedef __attribute__((ext_vector_type(8)))  short bf16x8;
typedef __attribute__((ext_vector_type(4)))  float f32x4;
typedef __attribute__((ext_vector_type(16))) float f32x16;
typedef __attribute__((ext_vector_type(4)))  u16  u16x4;
typedef __attribute__((ext_vector_type(8)))  u16  u16x8;

#define AS1C(p) ((const __attribute__((address_space(1))) void*)(p))
#define AS3(p)  ((__attribute__((address_space(3))) void*)(p))

__device__ __forceinline__ u16 f2bf(float f) {
  union { float f; unsigned u; } v; v.f = f;
  unsigned u = v.u;
  return (u16)((u + 0x7fffu + ((u >> 16) & 1u)) >> 16);  // RNE
}

// one-instruction pack: {lo16 = bf16(a), hi16 = bf16(b)}  (gfx950 v_cvt_pk_bf16_f32, RNE)
__device__ __forceinline__ u32 pk_bf16(float a, float b) {
  u32 r;
  asm("v_cvt_pk_bf16_f32 %0, %1, %2" : "=v"(r) : "v"(a), "v"(b));
  return r;
}
// raw hardware exp2 (v_exp_f32 IS 2^x) — log2e folded into the Q scale upstream
__device__ __forceinline__ float exp2fast(float x) {
  float r;
  asm("v_exp_f32 %0, %1" : "=v"(r) : "v"(x));
  return r;
}
__device__ __forceinline__ float bf2f(u16 b) {
  union { u32 u; float f; } v; v.u = ((u32)b) << 16; return v.f;
}

__device__ __forceinline__ f32x4 mfma16(bf16x8 a, bf16x8 b, f32x4 c) {
  return __builtin_amdgcn_mfma_f32_16x16x32_bf16(a, b, c, 0, 0, 0);
}
__device__ __forceinline__ f32x16 mfma32(bf16x8 a, bf16x8 b, f32x16 c) {
  return __builtin_amdgcn_mfma_f32_32x32x16_bf16(a, b, c, 0, 0, 0);
}

// ---------------- prep: fp32->bf16 for x and W's, concat biases ----------------
__global__ __launch_bounds__(256) void prep_kernel(
    const float* __restrict__ x,
    const float* __restrict__ wq, const float* __restrict__ wk,
    const float* __restrict__ wv, const float* __restrict__ wo,
    const float* __restrict__ bq, const float* __restrict__ bk, const float* __restrict__ bv,
    u16* __restrict__ xb, u16* __restrict__ wb, float* __restrict__ bc)
{
  int ch = blockIdx.x * 256 + threadIdx.x;
  if (ch < 2097152) {
    const float* src; u16* dst;
    if (ch < 1048576) { src = x + ch * 4; dst = xb + ch * 4; }
    else {
      int c2 = ch - 1048576;
      int wsel = c2 >> 18;
      int off  = c2 & 262143;
      const float* wsrc[4] = { wq, wk, wv, wo };
      src = wsrc[wsel] + off * 4;
      dst = wb + wsel * 1048576 + off * 4;
    }
    f32x4 v = *(const f32x4*)src;
    union { u32 u[2]; u16x4 v4; } o;
    o.u[0] = pk_bf16(v[0], v[1]);
    o.u[1] = pk_bf16(v[2], v[3]);
    *(u16x4*)dst = o.v4;
  } else {
    int c3 = ch - 2097152;            // < 768
    int bsel = c3 >> 8, off = c3 & 255;
    const float* bsrc[3] = { bq, bk, bv };
    f32x4 v = *(const f32x4*)(bsrc[bsel] + off * 4);
    *(f32x4*)(bc + bsel * 1024 + off * 4) = v;
  }
}

// ---------------- QKV GEMM: 128x128, BK=32, 4 waves, 3-buf counted vmcnt + setprio ----------------
// r11-proven optimum (57-62us). Per K-step: vmcnt(4) -> s_barrier -> STAGE(t+2) -> COMPUTE(t).
// 48KB LDS -> 3 blocks/CU (12 waves/CU). Design-space sweep (r2..r13): 2-phase drain 63.5,
// 4-buf/2blk 96.5, 8-phase-256^2 87, 8-wave 80.5, no-setprio 105 -> THIS config wins:
//  - s_setprio(1) around MFMA cluster: ESSENTIAL (r9 A/B: removing = 59.5->105.5us)
//  - 16 MFMA/wave/step cluster length: ESSENTIAL (r12: halving = 61->80.5us)
//  - block map keeps all 8 writers of each V^T 128B line on one XCD (r5: else 3x write amp)
// Q scale = 0.125*log2(e) -> attention softmax runs in exp2 domain.
__global__ __launch_bounds__(256) void gemm_qkv(
    const u16* __restrict__ A, const u16* __restrict__ Bw,
    const float* __restrict__ bias, u16* __restrict__ outb)
{
  __shared__ u16 As[3][4096];
  __shared__ u16 Bs[3][4096];

  const int K = 1024;
  int tid = threadIdx.x, w = tid >> 6, lane = tid & 63;
  int g = lane >> 4, lr = lane & 15;
  int wr = w >> 1, wcn = w & 1;

  int bid = blockIdx.x;
  int bm = (bid & 7) + 8 * ((bid >> 3) & 3);
  int bn = bid >> 5;

  int ch0 = tid, ch1 = tid + 256;
  auto srcoff = [&](int ch) -> size_t {
    int r = ch >> 2, pc = ch & 3;
    int gc = pc ^ ((r >> 2) & 3);        // source pre-swizzle (involution)
    return (size_t)r * K + gc * 8;
  };
  const u16* aS0 = A  + (size_t)(bm * 128) * K + srcoff(ch0);
  const u16* aS1 = A  + (size_t)(bm * 128) * K + srcoff(ch1);
  const u16* bS0 = Bw + (size_t)(bn * 128) * K + srcoff(ch0);
  const u16* bS1 = Bw + (size_t)(bn * 128) * K + srcoff(ch1);
  int lo0 = ch0 * 8, lo1 = ch1 * 8;

  auto STAGE = [&](int buf, int kt) {
    __builtin_amdgcn_global_load_lds(AS1C(aS0 + kt * 32), AS3(&As[buf][lo0]), 16, 0, 0);
    __builtin_amdgcn_global_load_lds(AS1C(aS1 + kt * 32), AS3(&As[buf][lo1]), 16, 0, 0);
    __builtin_amdgcn_global_load_lds(AS1C(bS0 + kt * 32), AS3(&Bs[buf][lo0]), 16, 0, 0);
    __builtin_amdgcn_global_load_lds(AS1C(bS1 + kt * 32), AS3(&Bs[buf][lo1]), 16, 0, 0);
  };

  f32x4 acc[4][4] = {};
  int pc8 = (g ^ ((lr >> 2) & 3)) * 8;   // swizzled read chunk

  auto COMPUTE = [&](int buf) {
    bf16x8 af[4], bfr[4];
#pragma unroll
    for (int m = 0; m < 4; ++m)
      af[m] = *(const bf16x8*)&As[buf][(wr * 64 + m * 16 + lr) * 32 + pc8];
#pragma unroll
    for (int n = 0; n < 4; ++n)
      bfr[n] = *(const bf16x8*)&Bs[buf][(wcn * 64 + n * 16 + lr) * 32 + pc8];
    __builtin_amdgcn_s_setprio(1);
#pragma unroll
    for (int m = 0; m < 4; ++m)
#pragma unroll
      for (int n = 0; n < 4; ++n)
        acc[m][n] = mfma16(af[m], bfr[n], acc[m][n]);
    __builtin_amdgcn_s_setprio(0);
  };

  STAGE(0, 0); STAGE(1, 1);

  int sb = 2, cb = 0;
  for (int t = 0; t < 31; ++t) {
    asm volatile("s_waitcnt vmcnt(4)" ::: "memory");  // tile t landed; t+1 in flight
    __builtin_amdgcn_s_barrier();
    asm volatile("" ::: "memory");
    if (t < 30) {
      STAGE(sb, t + 2);
      if (++sb == 3) sb = 0;
    }
    COMPUTE(cb);
    if (++cb == 3) cb = 0;
  }
  asm volatile("s_waitcnt vmcnt(0)" ::: "memory");
  __builtin_amdgcn_s_barrier();
  asm volatile("" ::: "memory");
  COMPUTE(cb);

  // epilogue: D layout col=lane&15, row=(lane>>4)*4+i
#pragma unroll
  for (int m = 0; m < 4; ++m) {
    int row0 = bm * 128 + wr * 64 + m * 16 + 4 * g;
#pragma unroll
    for (int n = 0; n < 4; ++n) {
      int col = bn * 128 + wcn * 64 + n * 16 + lr;
#pragma unroll
      for (int i = 0; i < 4; ++i) {
        float v = acc[m][n][i] + bias[col];
        int r = row0 + i;
        if (col < 1024) {
          outb[(size_t)r * 1024 + col] = f2bf(v * 0.18033688f);           // Q * (1/8)*log2(e)
        } else if (col < 2048) {
          outb[4194304 + (size_t)r * 1024 + (col - 1024)] = f2bf(v);     // K
        } else {
          int c = col - 2048;
          // V^T[bh=r>>6][dh=c&63][k=(r&63)*16+(c>>6)]
          outb[8388608 + (size_t)(r >> 6) * 65536 + (size_t)(c & 63) * 1024
               + (r & 63) * 16 + (c >> 6)] = f2bf(v);
        }
      }
    }
  }
}

// ---------------- out-proj GEMM: 64x128 tile, BK=32, 4 waves, 3-buf counted + setprio ----------------
// Writes proj = ctx*Wo^T + bo as bf16 ONLY (8MB); residual-add lives in ln_kernel (r14: -3us).
__global__ __launch_bounds__(256) void gemm_op(
    const u16* __restrict__ A, const u16* __restrict__ Bw,
    const float* __restrict__ bias, u16* __restrict__ outp)
{
  __shared__ u16 As[3][2048];    // [64][32] per buffer
  __shared__ u16 Bs[3][4096];    // [128][32]

  const int K = 1024;
  int tid = threadIdx.x, w = tid >> 6, lane = tid & 63;
  int g = lane >> 4, lr = lane & 15;
  int wr = w >> 1, wcn = w & 1;
  int bid = blockIdx.x;
  int bm = bid & 63, bn = bid >> 6;      // grid 512 = 64 x 8

  auto srcoff = [&](int ch) -> size_t {
    int r = ch >> 2, pc = ch & 3;
    int gc = pc ^ ((r >> 2) & 3);
    return (size_t)r * K + gc * 8;
  };
  const u16* aS0 = A  + (size_t)(bm * 64)  * K + srcoff(tid);
  const u16* bS0 = Bw + (size_t)(bn * 128) * K + srcoff(tid);
  const u16* bS1 = Bw + (size_t)(bn * 128) * K + srcoff(tid + 256);

  auto STAGE = [&](int buf, int kt) {
    __builtin_amdgcn_global_load_lds(AS1C(aS0 + kt * 32), AS3(&As[buf][tid * 8]),        16, 0, 0);
    __builtin_amdgcn_global_load_lds(AS1C(bS0 + kt * 32), AS3(&Bs[buf][tid * 8]),        16, 0, 0);
    __builtin_amdgcn_global_load_lds(AS1C(bS1 + kt * 32), AS3(&Bs[buf][2048 + tid * 8]), 16, 0, 0);
  };

  f32x4 acc[2][4] = {};
  int pc8 = (g ^ ((lr >> 2) & 3)) * 8;

  auto COMPUTE = [&](int buf) {
    bf16x8 af[2], bfr[4];
#pragma unroll
    for (int m = 0; m < 2; ++m)
      af[m] = *(const bf16x8*)&As[buf][(wr * 32 + m * 16 + lr) * 32 + pc8];
#pragma unroll
    for (int n = 0; n < 4; ++n)
      bfr[n] = *(const bf16x8*)&Bs[buf][(wcn * 64 + n * 16 + lr) * 32 + pc8];
    __builtin_amdgcn_s_setprio(1);
#pragma unroll
    for (int m = 0; m < 2; ++m)
#pragma unroll
      for (int n = 0; n < 4; ++n)
        acc[m][n] = mfma16(af[m], bfr[n], acc[m][n]);
    __builtin_amdgcn_s_setprio(0);
  };

  STAGE(0, 0); STAGE(1, 1);

  int sb = 2, cb = 0;
  for (int t = 0; t < 31; ++t) {
    asm volatile("s_waitcnt vmcnt(3)" ::: "memory");
    __builtin_amdgcn_s_barrier();
    asm volatile("" ::: "memory");
    if (t < 30) {
      STAGE(sb, t + 2);
      if (++sb == 3) sb = 0;
    }
    COMPUTE(cb);
    if (++cb == 3) cb = 0;
  }
  asm volatile("s_waitcnt vmcnt(0)" ::: "memory");
  __builtin_amdgcn_s_barrier();
  asm volatile("" ::: "memory");
  COMPUTE(cb);

#pragma unroll
  for (int m = 0; m < 2; ++m) {
    int row0 = bm * 64 + wr * 32 + m * 16 + 4 * g;
#pragma unroll
    for (int n = 0; n < 4; ++n) {
      int col = bn * 128 + wcn * 64 + n * 16 + lr;
#pragma unroll
      for (int i = 0; i < 4; ++i)
        outp[(size_t)(row0 + i) * 1024 + col] = f2bf(acc[m][n][i] + bias[col]);
    }
  }
}

// ---------------- flash attention, 32x32 swapped-operand, NO LDS (L1/L2-direct) ----------------
// r15: K/V are L1/L2-resident (per head 256KB; bh=blk&63 pins a head's 8 blocks to one XCD;
// a block's 4 waves read the SAME 16KB tile -> L1 serves 3 of 4). LDS staging + 32 barriers +
// counted vmcnt were re-buying cached data (Common-mistake #7 / m169). Now: MFMA operands load
// straight from global; waves fully independent (zero barriers, zero LDS). K double-buffered
// in registers (static A/B sets via 2-unrolled loop, rule #20-safe); V issued right after QK^T,
// latency hides under softmax. Math byte-identical to r14 (refcheck'd absmax 0.03125):
//   S^T = mfma32(K,Q), exp2-domain softmax (Q pre-scaled 0.125*log2e), defer-max THR=11,
//   cvt_pk pack, one hi/lo exchange for the PV B-frag, O^T = mfma32(V^T, P).
__global__ __launch_bounds__(256) void attn_kernel(
    const u16* __restrict__ Qb, const u16* __restrict__ Kb,
    const u16* __restrict__ Vtb, u16* __restrict__ Ob)
{
  int blk = blockIdx.x;
  int bh = blk & 63, qt = blk >> 6;          // head h on XCD h%8 -> K/V L2-resident
  int tid = threadIdx.x, wid = tid >> 6, lane = tid & 63;
  int l31 = lane & 31, hi = lane >> 5;

  const u16* Qp = Qb  + (size_t)bh * 65536;
  const u16* Kp = Kb  + (size_t)bh * 65536;
  const u16* Vp = Vtb + (size_t)bh * 65536;

  int q = qt * 128 + wid * 32 + l31;

  // Q as B-operand: lane holds Q[q][s*16+hi*8 .. +8] per 16-k step s
  bf16x8 qf[4];
#pragma unroll
  for (int s = 0; s < 4; ++s)
    qf[s] = *(const bf16x8*)&Qp[(size_t)q * 64 + s * 16 + hi * 8];

  f32x16 oacc[2] = {};
  float mrow = -3e38f, lrow = 0.f;

  // fragment bases (u16 units):
  //   K frag (tile kt, ks, s): Kp[(kt*64 + ks*32 + l31)*64 + s*16 + hi*8]
  //   V frag (tile kt, dt, s): Vp[(dt*32 + l31)*1024 + kt*64 + s*16 + hi*8]
  const u16* kbase = Kp + (size_t)l31 * 64 + hi * 8;
  const u16* vbase = Vp + (size_t)l31 * 1024 + hi * 8;

  auto LOADK = [&](bf16x8 (&kf)[2][4], int kt) {
#pragma unroll
    for (int ks = 0; ks < 2; ++ks)
#pragma unroll
      for (int s = 0; s < 4; ++s)
        kf[ks][s] = *(const bf16x8*)&kbase[kt * 4096 + ks * 2048 + s * 16];
  };

  auto BODY = [&](bf16x8 (&cur)[2][4], bf16x8 (&nxt)[2][4], int kt) {
    // --- S^T = K Q^T (log2-domain scores)
    f32x16 s2[2];
#pragma unroll
    for (int ks = 0; ks < 2; ++ks) {
      f32x16 z = {};
      __builtin_amdgcn_s_setprio(1);
#pragma unroll
      for (int s = 0; s < 4; ++s)
        z = mfma32(cur[ks][s], qf[s], z);
      __builtin_amdgcn_s_setprio(0);
      s2[ks] = z;
    }

    // --- prefetch next tile's K; issue this tile's V (consumed after softmax)
    if (kt + 1 < 16) LOADK(nxt, kt + 1);
    bf16x8 vf[2][4];
#pragma unroll
    for (int dt = 0; dt < 2; ++dt)
#pragma unroll
      for (int s = 0; s < 4; ++s)
        vf[dt][s] = *(const bf16x8*)&vbase[(size_t)dt * 32768 + kt * 64 + s * 16];

    // --- online softmax, in-register (lane owns row q), defer-max THR=11 (log2)
    float tv[16];
#pragma unroll
    for (int r = 0; r < 16; ++r) tv[r] = fmaxf(s2[0][r], s2[1][r]);
#pragma unroll
    for (int st = 8; st > 0; st >>= 1)
#pragma unroll
      for (int r = 0; r < st; ++r) tv[r] = fmaxf(tv[r], tv[r + st]);
    float tm = fmaxf(tv[0], __shfl_xor(tv[0], 32));

    bool nores = __all(tm - mrow <= 11.0f);
    float mn, corr;
    if (nores) { mn = mrow; corr = 1.f; }
    else       { mn = fmaxf(mrow, tm); corr = exp2fast(mrow - mn); }

    float sv[16];
#pragma unroll
    for (int r = 0; r < 16; ++r) {
      s2[0][r] = exp2fast(s2[0][r] - mn);
      s2[1][r] = exp2fast(s2[1][r] - mn);
      sv[r] = s2[0][r] + s2[1][r];
    }
#pragma unroll
    for (int st = 8; st > 0; st >>= 1)
#pragma unroll
      for (int r = 0; r < st; ++r) sv[r] += sv[r + st];
    float rs = sv[0] + __shfl_xor(sv[0], 32);

    if (nores) {
      lrow += rs;
    } else {
#pragma unroll
      for (int dt = 0; dt < 2; ++dt)
#pragma unroll
        for (int r = 0; r < 16; ++r) oacc[dt][r] *= corr;
      lrow = lrow * corr + rs;
      mrow = mn;
    }

    // --- pack P to bf16 pairs via cvt_pk: w[ks][r1][p] = {k=4hi+8r1+2p, +1}
    u32 wpk[2][4][2];
#pragma unroll
    for (int ks = 0; ks < 2; ++ks)
#pragma unroll
      for (int r1 = 0; r1 < 4; ++r1)
#pragma unroll
        for (int p = 0; p < 2; ++p)
          wpk[ks][r1][p] = pk_bf16(s2[ks][4 * r1 + 2 * p], s2[ks][4 * r1 + 2 * p + 1]);

    // --- PV: 4 k-steps of 16; build pb via one hi/lo exchange (r8-verified)
#pragma unroll
    for (int s = 0; s < 4; ++s) {
      int ks = s >> 1, t = s & 1;
      u32 a0 = wpk[ks][2 * t][0],     a1 = wpk[ks][2 * t][1];
      u32 b0 = wpk[ks][2 * t + 1][0], b1 = wpk[ks][2 * t + 1][1];
      u32 sa0 = (u32)__shfl_xor((int)a0, 32), sa1 = (u32)__shfl_xor((int)a1, 32);
      u32 sb0 = (u32)__shfl_xor((int)b0, 32), sb1 = (u32)__shfl_xor((int)b1, 32);
      union { u32 u[4]; bf16x8 v; } pb;
      pb.u[0] = hi ? sb0 : a0;
      pb.u[1] = hi ? sb1 : a1;
      pb.u[2] = hi ? b0 : sa0;
      pb.u[3] = hi ? b1 : sa1;
      __builtin_amdgcn_s_setprio(1);
#pragma unroll
      for (int dt = 0; dt < 2; ++dt)
        oacc[dt] = mfma32(vf[dt][s], pb.v, oacc[dt]);
      __builtin_amdgcn_s_setprio(0);
    }
  };

  bf16x8 kfA[2][4], kfB[2][4];
  LOADK(kfA, 0);
  for (int t2 = 0; t2 < 8; ++t2) {
    BODY(kfA, kfB, 2 * t2);
    BODY(kfB, kfA, 2 * t2 + 1);
  }

  // epilogue: ctx[q][d] = O^T[d][q] / lrow ; d_local(reg r) = (r&3)+8*(r>>2)+4hi
  float inv = 1.f / lrow;
  u16* Op = Ob + (size_t)bh * 65536 + (size_t)q * 64;
#pragma unroll
  for (int dt = 0; dt < 2; ++dt)
#pragma unroll
    for (int rq = 0; rq < 4; ++rq) {
      int d0 = dt * 32 + 8 * rq + 4 * hi;
      union { u32 u[2]; u16x4 v; } o4;
      o4.u[0] = pk_bf16(oacc[dt][4 * rq + 0] * inv, oacc[dt][4 * rq + 1] * inv);
      o4.u[1] = pk_bf16(oacc[dt][4 * rq + 2] * inv, oacc[dt][4 * rq + 3] * inv);
      *(u16x4*)&Op[d0] = o4.v;
    }
}

// ---------------- LayerNorm: out = LN(x + proj), rows of [4096][1024] ----------------
// Residual add fused here (r14): reads proj bf16 (8MB) + x f32 (16MB), writes out f32 (16MB).
__global__ __launch_bounds__(256) void ln_kernel(
    const float* __restrict__ xres, const u16* __restrict__ proj,
    float* __restrict__ out,
    const float* __restrict__ gamma, const float* __restrict__ beta)
{
  int row = blockIdx.x, tid = threadIdx.x;
  int lane = tid & 63, wid = tid >> 6;
  f32x4 xv = *(const f32x4*)&xres[(size_t)row * 1024 + tid * 4];
  u16x4 pv = *(const u16x4*)&proj[(size_t)row * 1024 + tid * 4];
  f32x4 v;
#pragma unroll
  for (int j = 0; j < 4; ++j) v[j] = xv[j] + bf2f(pv[j]);
  float s = v[0] + v[1] + v[2] + v[3];
  float q = v[0] * v[0] + v[1] * v[1] + v[2] * v[2] + v[3] * v[3];
#pragma unroll
  for (int ms = 1; ms < 64; ms <<= 1) { s += __shfl_xor(s, ms); q += __shfl_xor(q, ms); }
  __shared__ float red[8];
  if (lane == 0) { red[wid] = s; red[wid + 4] = q; }
  __syncthreads();
  s = red[0] + red[1] + red[2] + red[3];
  q = red[4] + red[5] + red[6] + red[7];
  float mu = s * (1.f / 1024.f);
  float var = q * (1.f / 1024.f) - mu * mu;
  float inv = rsqrtf(var + 1e-5f);
  f32x4 g4 = *(const f32x4*)&gamma[tid * 4];
  f32x4 b4 = *(const f32x4*)&beta[tid * 4];
  f32x4 o;
#pragma unroll
  for (int j = 0; j < 4; ++j) o[j] = (v[j] - mu) * inv * g4[j] + b4[j];
  *(f32x4*)&out[(size_t)row * 1024 + tid * 4] = o;
}

// ---------------- launch ----------------
extern "C" void kernel_launch(void* const* d_in, const int* in_sizes, int n_in,
                              void* d_out, int out_size, void* d_ws, size_t ws_size,
                              hipStream_t stream) {
  const float* x     = (const float*)d_in[0];
  const float* Wq    = (const float*)d_in[1];
  const float* bq    = (const float*)d_in[2];
  const float* Wk    = (const float*)d_in[3];
  const float* bk    = (const float*)d_in[4];
  const float* Wv    = (const float*)d_in[5];
  const float* bv    = (const float*)d_in[6];
  const float* Wo    = (const float*)d_in[7];
  const float* bo    = (const float*)d_in[8];
  const float* gamma = (const float*)d_in[9];
  const float* beta  = (const float*)d_in[10];
  float* out = (float*)d_out;

  char* ws = (char*)d_ws;
  u16*   xb  = (u16*)ws;                                   // 8MB  [4096][1024] bf16 (reused as ctx)
  u16*   wb  = (u16*)(ws + (8u << 20));                    // 8MB  Wq|Wk|Wv|Wo bf16
  float* bc  = (float*)(ws + (16u << 20));                 // 12KB bq|bk|bv
  u16*   qkv = (u16*)(ws + (16u << 20) + 16384);           // 24MB Q | K | V^T bf16
  u16*   ctx = xb;                                         // overlay: xb dead after QKV GEMM
  u16*   proj = qkv;                                       // overlay: Q dead after attention

  prep_kernel<<<8195, 256, 0, stream>>>(x, Wq, Wk, Wv, Wo, bq, bk, bv, xb, wb, bc);

  // QKV: M=4096 x N=3072 -> grid 768 (bm=(bid&7)+8*((bid>>3)&3), bn=bid>>5)
  gemm_qkv<<<768, 256, 0, stream>>>(xb, wb, bc, qkv);

  // attention: 512 blocks x 256 threads (4 waves x 32 q), 128 q/block, no LDS
  attn_kernel<<<512, 256, 0, stream>>>(qkv, qkv + 4194304, qkv + 8388608, ctx);

  // out-proj: M=4096 x N=1024, 64x128 tiles -> grid 512; writes proj bf16 only
  gemm_op<<<512, 256, 0, stream>>>(ctx, wb + 3 * 1048576, bo, proj);

  // LN with fused residual: out = LN(x + proj)
  ln_kernel<<<4096, 256, 0, stream>>>(x, proj, out, gamma, beta);
}

// Round 20
// 122.568 us; speedup vs baseline: 1.2305x; 1.2237x over previous
//
#include <hip/hip_runtime.h>
#include <hip/hip_bf16.h>

// B=4 S=1024 D=1024 H=16 DH=64 -> flat M=4096, attention raw view [64][1024][64]

using u16 = unsigned short;
using u32 = unsigned int;
typedef __attribute__((ext_vector_type(8)))  short bf16x8;
typedef __attribute__((ext_vector_type(4)))  float f32x4;
typedef __attribute__((ext_vector_type(16))) float f32x16;
typedef __attribute__((ext_vector_type(4)))  u16  u16x4;
typedef __attribute__((ext_vector_type(8)))  u16  u16x8;

#define AS1C(p) ((const __attribute__((address_space(1))) void*)(p))
#define AS3(p)  ((__attribute__((address_space(3))) void*)(p))

__device__ __forceinline__ u16 f2bf(float f) {
  union { float f; unsigned u; } v; v.f = f;
  unsigned u = v.u;
  return (u16)((u + 0x7fffu + ((u >> 16) & 1u)) >> 16);  // RNE
}

// one-instruction pack: {lo16 = bf16(a), hi16 = bf16(b)}  (gfx950 v_cvt_pk_bf16_f32, RNE)
__device__ __forceinline__ u32 pk_bf16(float a, float b) {
  u32 r;
  asm("v_cvt_pk_bf16_f32 %0, %1, %2" : "=v"(r) : "v"(a), "v"(b));
  return r;
}
// raw hardware exp2 (v_exp_f32 IS 2^x) — log2e folded into the Q scale upstream
__device__ __forceinline__ float exp2fast(float x) {
  float r;
  asm("v_exp_f32 %0, %1" : "=v"(r) : "v"(x));
  return r;
}
__device__ __forceinline__ float bf2f(u16 b) {
  union { u32 u; float f; } v; v.u = ((u32)b) << 16; return v.f;
}

__device__ __forceinline__ f32x4 mfma16(bf16x8 a, bf16x8 b, f32x4 c) {
  return __builtin_amdgcn_mfma_f32_16x16x32_bf16(a, b, c, 0, 0, 0);
}
__device__ __forceinline__ f32x16 mfma32(bf16x8 a, bf16x8 b, f32x16 c) {
  return __builtin_amdgcn_mfma_f32_32x32x16_bf16(a, b, c, 0, 0, 0);
}

// ---------------- prep: fp32->bf16 for x and W's, concat biases ----------------
__global__ __launch_bounds__(256) void prep_kernel(
    const float* __restrict__ x,
    const float* __restrict__ wq, const float* __restrict__ wk,
    const float* __restrict__ wv, const float* __restrict__ wo,
    const float* __restrict__ bq, const float* __restrict__ bk, const float* __restrict__ bv,
    u16* __restrict__ xb, u16* __restrict__ wb, float* __restrict__ bc)
{
  int ch = blockIdx.x * 256 + threadIdx.x;
  if (ch < 2097152) {
    const float* src; u16* dst;
    if (ch < 1048576) { src = x + ch * 4; dst = xb + ch * 4; }
    else {
      int c2 = ch - 1048576;
      int wsel = c2 >> 18;
      int off  = c2 & 262143;
      const float* wsrc[4] = { wq, wk, wv, wo };
      src = wsrc[wsel] + off * 4;
      dst = wb + wsel * 1048576 + off * 4;
    }
    f32x4 v = *(const f32x4*)src;
    union { u32 u[2]; u16x4 v4; } o;
    o.u[0] = pk_bf16(v[0], v[1]);
    o.u[1] = pk_bf16(v[2], v[3]);
    *(u16x4*)dst = o.v4;
  } else {
    int c3 = ch - 2097152;            // < 768
    int bsel = c3 >> 8, off = c3 & 255;
    const float* bsrc[3] = { bq, bk, bv };
    f32x4 v = *(const f32x4*)(bsrc[bsel] + off * 4);
    *(f32x4*)(bc + bsel * 1024 + off * 4) = v;
  }
}

// ---------------- QKV GEMM: 128x128, BK=32, 4 waves, 3-buf counted vmcnt + setprio ----------------
// r11-proven optimum (57-62us). Per K-step: vmcnt(4) -> s_barrier -> STAGE(t+2) -> COMPUTE(t).
// 48KB LDS -> 3 blocks/CU (12 waves/CU). Design-space sweep (r2..r13): 2-phase drain 63.5,
// 4-buf/2blk 96.5, 8-phase-256^2 87, 8-wave 80.5, no-setprio 105 -> THIS config wins:
//  - s_setprio(1) around MFMA cluster: ESSENTIAL (r9 A/B: removing = 59.5->105.5us)
//  - 16 MFMA/wave/step cluster length: ESSENTIAL (r12: halving = 61->80.5us)
//  - block map keeps all 8 writers of each V^T 128B line on one XCD (r5: else 3x write amp)
// Q scale = 0.125*log2(e) -> attention softmax runs in exp2 domain.
__global__ __launch_bounds__(256) void gemm_qkv(
    const u16* __restrict__ A, const u16* __restrict__ Bw,
    const float* __restrict__ bias, u16* __restrict__ outb)
{
  __shared__ u16 As[3][4096];
  __shared__ u16 Bs[3][4096];

  const int K = 1024;
  int tid = threadIdx.x, w = tid >> 6, lane = tid & 63;
  int g = lane >> 4, lr = lane & 15;
  int wr = w >> 1, wcn = w & 1;

  int bid = blockIdx.x;
  int bm = (bid & 7) + 8 * ((bid >> 3) & 3);
  int bn = bid >> 5;

  int ch0 = tid, ch1 = tid + 256;
  auto srcoff = [&](int ch) -> size_t {
    int r = ch >> 2, pc = ch & 3;
    int gc = pc ^ ((r >> 2) & 3);        // source pre-swizzle (involution)
    return (size_t)r * K + gc * 8;
  };
  const u16* aS0 = A  + (size_t)(bm * 128) * K + srcoff(ch0);
  const u16* aS1 = A  + (size_t)(bm * 128) * K + srcoff(ch1);
  const u16* bS0 = Bw + (size_t)(bn * 128) * K + srcoff(ch0);
  const u16* bS1 = Bw + (size_t)(bn * 128) * K + srcoff(ch1);
  int lo0 = ch0 * 8, lo1 = ch1 * 8;

  auto STAGE = [&](int buf, int kt) {
    __builtin_amdgcn_global_load_lds(AS1C(aS0 + kt * 32), AS3(&As[buf][lo0]), 16, 0, 0);
    __builtin_amdgcn_global_load_lds(AS1C(aS1 + kt * 32), AS3(&As[buf][lo1]), 16, 0, 0);
    __builtin_amdgcn_global_load_lds(AS1C(bS0 + kt * 32), AS3(&Bs[buf][lo0]), 16, 0, 0);
    __builtin_amdgcn_global_load_lds(AS1C(bS1 + kt * 32), AS3(&Bs[buf][lo1]), 16, 0, 0);
  };

  f32x4 acc[4][4] = {};
  int pc8 = (g ^ ((lr >> 2) & 3)) * 8;   // swizzled read chunk

  auto COMPUTE = [&](int buf) {
    bf16x8 af[4], bfr[4];
#pragma unroll
    for (int m = 0; m < 4; ++m)
      af[m] = *(const bf16x8*)&As[buf][(wr * 64 + m * 16 + lr) * 32 + pc8];
#pragma unroll
    for (int n = 0; n < 4; ++n)
      bfr[n] = *(const bf16x8*)&Bs[buf][(wcn * 64 + n * 16 + lr) * 32 + pc8];
    __builtin_amdgcn_s_setprio(1);
#pragma unroll
    for (int m = 0; m < 4; ++m)
#pragma unroll
      for (int n = 0; n < 4; ++n)
        acc[m][n] = mfma16(af[m], bfr[n], acc[m][n]);
    __builtin_amdgcn_s_setprio(0);
  };

  STAGE(0, 0); STAGE(1, 1);

  int sb = 2, cb = 0;
  for (int t = 0; t < 31; ++t) {
    asm volatile("s_waitcnt vmcnt(4)" ::: "memory");  // tile t landed; t+1 in flight
    __builtin_amdgcn_s_barrier();
    asm volatile("" ::: "memory");
    if (t < 30) {
      STAGE(sb, t + 2);
      if (++sb == 3) sb = 0;
    }
    COMPUTE(cb);
    if (++cb == 3) cb = 0;
  }
  asm volatile("s_waitcnt vmcnt(0)" ::: "memory");
  __builtin_amdgcn_s_barrier();
  asm volatile("" ::: "memory");
  COMPUTE(cb);

  // epilogue: D layout col=lane&15, row=(lane>>4)*4+i
#pragma unroll
  for (int m = 0; m < 4; ++m) {
    int row0 = bm * 128 + wr * 64 + m * 16 + 4 * g;
#pragma unroll
    for (int n = 0; n < 4; ++n) {
      int col = bn * 128 + wcn * 64 + n * 16 + lr;
#pragma unroll
      for (int i = 0; i < 4; ++i) {
        float v = acc[m][n][i] + bias[col];
        int r = row0 + i;
        if (col < 1024) {
          outb[(size_t)r * 1024 + col] = f2bf(v * 0.18033688f);           // Q * (1/8)*log2(e)
        } else if (col < 2048) {
          outb[4194304 + (size_t)r * 1024 + (col - 1024)] = f2bf(v);     // K
        } else {
          int c = col - 2048;
          // V^T[bh=r>>6][dh=c&63][k=(r&63)*16+(c>>6)]
          outb[8388608 + (size_t)(r >> 6) * 65536 + (size_t)(c & 63) * 1024
               + (r & 63) * 16 + (c >> 6)] = f2bf(v);
        }
      }
    }
  }
}

// ---------------- out-proj GEMM: 64x128 tile, BK=32, 4 waves, 3-buf counted + setprio ----------------
// Writes proj = ctx*Wo^T + bo as bf16 ONLY (8MB); residual-add lives in ln_kernel (r14: -3us).
__global__ __launch_bounds__(256) void gemm_op(
    const u16* __restrict__ A, const u16* __restrict__ Bw,
    const float* __restrict__ bias, u16* __restrict__ outp)
{
  __shared__ u16 As[3][2048];    // [64][32] per buffer
  __shared__ u16 Bs[3][4096];    // [128][32]

  const int K = 1024;
  int tid = threadIdx.x, w = tid >> 6, lane = tid & 63;
  int g = lane >> 4, lr = lane & 15;
  int wr = w >> 1, wcn = w & 1;
  int bid = blockIdx.x;
  int bm = bid & 63, bn = bid >> 6;      // grid 512 = 64 x 8

  auto srcoff = [&](int ch) -> size_t {
    int r = ch >> 2, pc = ch & 3;
    int gc = pc ^ ((r >> 2) & 3);
    return (size_t)r * K + gc * 8;
  };
  const u16* aS0 = A  + (size_t)(bm * 64)  * K + srcoff(tid);
  const u16* bS0 = Bw + (size_t)(bn * 128) * K + srcoff(tid);
  const u16* bS1 = Bw + (size_t)(bn * 128) * K + srcoff(tid + 256);

  auto STAGE = [&](int buf, int kt) {
    __builtin_amdgcn_global_load_lds(AS1C(aS0 + kt * 32), AS3(&As[buf][tid * 8]),        16, 0, 0);
    __builtin_amdgcn_global_load_lds(AS1C(bS0 + kt * 32), AS3(&Bs[buf][tid * 8]),        16, 0, 0);
    __builtin_amdgcn_global_load_lds(AS1C(bS1 + kt * 32), AS3(&Bs[buf][2048 + tid * 8]), 16, 0, 0);
  };

  f32x4 acc[2][4] = {};
  int pc8 = (g ^ ((lr >> 2) & 3)) * 8;

  auto COMPUTE = [&](int buf) {
    bf16x8 af[2], bfr[4];
#pragma unroll
    for (int m = 0; m < 2; ++m)
      af[m] = *(const bf16x8*)&As[buf][(wr * 32 + m * 16 + lr) * 32 + pc8];
#pragma unroll
    for (int n = 0; n < 4; ++n)
      bfr[n] = *(const bf16x8*)&Bs[buf][(wcn * 64 + n * 16 + lr) * 32 + pc8];
    __builtin_amdgcn_s_setprio(1);
#pragma unroll
    for (int m = 0; m < 2; ++m)
#pragma unroll
      for (int n = 0; n < 4; ++n)
        acc[m][n] = mfma16(af[m], bfr[n], acc[m][n]);
    __builtin_amdgcn_s_setprio(0);
  };

  STAGE(0, 0); STAGE(1, 1);

  int sb = 2, cb = 0;
  for (int t = 0; t < 31; ++t) {
    asm volatile("s_waitcnt vmcnt(3)" ::: "memory");
    __builtin_amdgcn_s_barrier();
    asm volatile("" ::: "memory");
    if (t < 30) {
      STAGE(sb, t + 2);
      if (++sb == 3) sb = 0;
    }
    COMPUTE(cb);
    if (++cb == 3) cb = 0;
  }
  asm volatile("s_waitcnt vmcnt(0)" ::: "memory");
  __builtin_amdgcn_s_barrier();
  asm volatile("" ::: "memory");
  COMPUTE(cb);

#pragma unroll
  for (int m = 0; m < 2; ++m) {
    int row0 = bm * 64 + wr * 32 + m * 16 + 4 * g;
#pragma unroll
    for (int n = 0; n < 4; ++n) {
      int col = bn * 128 + wcn * 64 + n * 16 + lr;
#pragma unroll
      for (int i = 0; i < 4; ++i)
        outp[(size_t)(row0 + i) * 1024 + col] = f2bf(acc[m][n][i] + bias[col]);
    }
  }
}

// ---------------- flash attention, 32x32 swapped-operand + 3-buf counted vmcnt + setprio ----------------
// r14-proven (~30us). REVERTED from the r15/r19 no-LDS variant (75us, VMEM-issue-bound):
// direct MFMA-fragment loads have lanes at 128B/2KB stride -> each global_load_dwordx4 touches
// 32-64 cache lines and serializes. LDS staging IS the coalescing transformer (1KB contiguous
// per wave via global_load_lds) — do not remove it.
// View [64 bh][1024 k][64 d]. 4 waves/block, 32 q/wave (QBLK=128), KV-tile 64, 512 blocks.
// Per tile t: vmcnt(4) -> s_barrier -> STAGE(t+2) -> compute(t); mod-3 buffers, prefetch 2.
//   S^T = mfma32(K,Q): lane owns all 64 S-values of q=lane&31 (Q pre-scaled by (1/8)*log2e
//   -> softmax in exp2 domain: raw v_exp_f32). Defer-max THR=11 (log2) ~ e^8.
//   P pack via v_cvt_pk_bf16_f32; P->PV B-frag via one hi/lo exchange (r8-verified).
__global__ __launch_bounds__(256) void attn_kernel(
    const u16* __restrict__ Qb, const u16* __restrict__ Kb,
    const u16* __restrict__ Vtb, u16* __restrict__ Ob)
{
  __shared__ u16 Ks[3][4096];    // [k_local 64][d 64], 16B-chunk XOR swizzle c^(r&7)
  __shared__ u16 Vts[3][4096];   // [d 64][k_local 64], same swizzle

  int blk = blockIdx.x;
  int bh = blk & 63, qt = blk >> 6;          // head h always on XCD h%8 -> K/V L2-resident
  int tid = threadIdx.x, wid = tid >> 6, lane = tid & 63;
  int l31 = lane & 31, hi = lane >> 5;

  const u16* Qp = Qb  + (size_t)bh * 65536;
  const u16* Kp = Kb  + (size_t)bh * 65536;
  const u16* Vp = Vtb + (size_t)bh * 65536;

  int q = qt * 128 + wid * 32 + l31;

  // Q as B-operand: lane holds Q[q][s*16+hi*8 .. +8] per 16-k step s
  bf16x8 qf[4];
#pragma unroll
  for (int s = 0; s < 4; ++s)
    qf[s] = *(const bf16x8*)&Qp[(size_t)q * 64 + s * 16 + hi * 8];

  f32x16 oacc[2] = {};
  float mrow = -3e38f, lrow = 0.f;

  // staging: 512 chunks of 16B per operand per tile; 256 threads -> 2 chunks each
  const u16* gk[2]; const u16* gv[2];
#pragma unroll
  for (int j = 0; j < 2; ++j) {
    int ch = tid + 256 * j;
    int kc = ch >> 3, scc = ch & 7;
    int sc = scc ^ (kc & 7);                     // pre-swizzled source chunk
    gk[j] = Kp + (size_t)kc * 64   + sc * 8;     // + kt*4096
    gv[j] = Vp + (size_t)kc * 1024 + sc * 8;     // row=dh, + kt*64
  }

  auto STAGE = [&](int buf, int kt) {
#pragma unroll
    for (int j = 0; j < 2; ++j) {
      int ch = tid + 256 * j;
      __builtin_amdgcn_global_load_lds(AS1C(gk[j] + (size_t)kt * 4096), AS3(&Ks[buf][ch * 8]),  16, 0, 0);
      __builtin_amdgcn_global_load_lds(AS1C(gv[j] + kt * 64),           AS3(&Vts[buf][ch * 8]), 16, 0, 0);
    }
  };

  STAGE(0, 0); STAGE(1, 1);

  int sb = 2, cb = 0;
  for (int kt = 0; kt < 16; ++kt) {
    if (kt < 15) { asm volatile("s_waitcnt vmcnt(4)" ::: "memory"); }
    else         { asm volatile("s_waitcnt vmcnt(0)" ::: "memory"); }
    __builtin_amdgcn_s_barrier();
    asm volatile("" ::: "memory");
    if (kt < 14) {
      STAGE(sb, kt + 2);
      if (++sb == 3) sb = 0;
    }

    // --- S^T = K Q^T (log2-domain scores)
    f32x16 s2[2];
#pragma unroll
    for (int ks = 0; ks < 2; ++ks) {
      f32x16 z = {};
      int row = ks * 32 + l31;
      int rx = (row & 7);
      __builtin_amdgcn_s_setprio(1);
#pragma unroll
      for (int s = 0; s < 4; ++s) {
        bf16x8 kb = *(const bf16x8*)&Ks[cb][row * 64 + (((2 * s + hi) ^ rx) * 8)];
        z = mfma32(kb, qf[s], z);
      }
      __builtin_amdgcn_s_setprio(0);
      s2[ks] = z;
    }

    // --- online softmax, in-register (lane owns row q), defer-max THR=11 (log2)
    float tv[16];
#pragma unroll
    for (int r = 0; r < 16; ++r) tv[r] = fmaxf(s2[0][r], s2[1][r]);
#pragma unroll
    for (int st = 8; st > 0; st >>= 1)
#pragma unroll
      for (int r = 0; r < st; ++r) tv[r] = fmaxf(tv[r], tv[r + st]);
    float tm = fmaxf(tv[0], __shfl_xor(tv[0], 32));

    bool nores = __all(tm - mrow <= 11.0f);
    float mn, corr;
    if (nores) { mn = mrow; corr = 1.f; }
    else       { mn = fmaxf(mrow, tm); corr = exp2fast(mrow - mn); }

    float sv[16];
#pragma unroll
    for (int r = 0; r < 16; ++r) {
      s2[0][r] = exp2fast(s2[0][r] - mn);
      s2[1][r] = exp2fast(s2[1][r] - mn);
      sv[r] = s2[0][r] + s2[1][r];
    }
#pragma unroll
    for (int st = 8; st > 0; st >>= 1)
#pragma unroll
      for (int r = 0; r < st; ++r) sv[r] += sv[r + st];
    float rs = sv[0] + __shfl_xor(sv[0], 32);

    if (nores) {
      lrow += rs;
    } else {
#pragma unroll
      for (int dt = 0; dt < 2; ++dt)
#pragma unroll
        for (int r = 0; r < 16; ++r) oacc[dt][r] *= corr;
      lrow = lrow * corr + rs;
      mrow = mn;
    }

    // --- pack P to bf16 pairs via cvt_pk: w[ks][r1][p] = {k=4hi+8r1+2p, +1}
    u32 wpk[2][4][2];
#pragma unroll
    for (int ks = 0; ks < 2; ++ks)
#pragma unroll
      for (int r1 = 0; r1 < 4; ++r1)
#pragma unroll
        for (int p = 0; p < 2; ++p)
          wpk[ks][r1][p] = pk_bf16(s2[ks][4 * r1 + 2 * p], s2[ks][4 * r1 + 2 * p + 1]);

    // --- PV: 4 k-steps of 16; build pb via one hi/lo exchange (r8-verified)
#pragma unroll
    for (int s = 0; s < 4; ++s) {
      int ks = s >> 1, t = s & 1;
      u32 a0 = wpk[ks][2 * t][0],     a1 = wpk[ks][2 * t][1];
      u32 b0 = wpk[ks][2 * t + 1][0], b1 = wpk[ks][2 * t + 1][1];
      u32 sa0 = (u32)__shfl_xor((int)a0, 32), sa1 = (u32)__shfl_xor((int)a1, 32);
      u32 sb0 = (u32)__shfl_xor((int)b0, 32), sb1 = (u32)__shfl_xor((int)b1, 32);
      union { u32 u[4]; bf16x8 v; } pb;
      pb.u[0] = hi ? sb0 : a0;
      pb.u[1] = hi ? sb1 : a1;
      pb.u[2] = hi ? b0 : sa0;
      pb.u[3] = hi ? b1 : sa1;
      __builtin_amdgcn_s_setprio(1);
#pragma unroll
      for (int dt = 0; dt < 2; ++dt) {
        int row = dt * 32 + l31;
        bf16x8 vb = *(const bf16x8*)&Vts[cb][row * 64 + (((2 * s + hi) ^ (row & 7)) * 8)];
        oacc[dt] = mfma32(vb, pb.v, oacc[dt]);
      }
      __builtin_amdgcn_s_setprio(0);
    }

    if (++cb == 3) cb = 0;
  }

  // epilogue: ctx[q][d] = O^T[d][q] / lrow ; d_local(reg r) = (r&3)+8*(r>>2)+4hi
  float inv = 1.f / lrow;
  u16* Op = Ob + (size_t)bh * 65536 + (size_t)q * 64;
#pragma unroll
  for (int dt = 0; dt < 2; ++dt)
#pragma unroll
    for (int rq = 0; rq < 4; ++rq) {
      int d0 = dt * 32 + 8 * rq + 4 * hi;
      union { u32 u[2]; u16x4 v; } o4;
      o4.u[0] = pk_bf16(oacc[dt][4 * rq + 0] * inv, oacc[dt][4 * rq + 1] * inv);
      o4.u[1] = pk_bf16(oacc[dt][4 * rq + 2] * inv, oacc[dt][4 * rq + 3] * inv);
      *(u16x4*)&Op[d0] = o4.v;
    }
}

// ---------------- LayerNorm: out = LN(x + proj), rows of [4096][1024] ----------------
// Residual add fused here (r14): reads proj bf16 (8MB) + x f32 (16MB), writes out f32 (16MB).
__global__ __launch_bounds__(256) void ln_kernel(
    const float* __restrict__ xres, const u16* __restrict__ proj,
    float* __restrict__ out,
    const float* __restrict__ gamma, const float* __restrict__ beta)
{
  int row = blockIdx.x, tid = threadIdx.x;
  int lane = tid & 63, wid = tid >> 6;
  f32x4 xv = *(const f32x4*)&xres[(size_t)row * 1024 + tid * 4];
  u16x4 pv = *(const u16x4*)&proj[(size_t)row * 1024 + tid * 4];
  f32x4 v;
#pragma unroll
  for (int j = 0; j < 4; ++j) v[j] = xv[j] + bf2f(pv[j]);
  float s = v[0] + v[1] + v[2] + v[3];
  float q = v[0] * v[0] + v[1] * v[1] + v[2] * v[2] + v[3] * v[3];
#pragma unroll
  for (int ms = 1; ms < 64; ms <<= 1) { s += __shfl_xor(s, ms); q += __shfl_xor(q, ms); }
  __shared__ float red[8];
  if (lane == 0) { red[wid] = s; red[wid + 4] = q; }
  __syncthreads();
  s = red[0] + red[1] + red[2] + red[3];
  q = red[4] + red[5] + red[6] + red[7];
  float mu = s * (1.f / 1024.f);
  float var = q * (1.f / 1024.f) - mu * mu;
  float inv = rsqrtf(var + 1e-5f);
  f32x4 g4 = *(const f32x4*)&gamma[tid * 4];
  f32x4 b4 = *(const f32x4*)&beta[tid * 4];
  f32x4 o;
#pragma unroll
  for (int j = 0; j < 4; ++j) o[j] = (v[j] - mu) * inv * g4[j] + b4[j];
  *(f32x4*)&out[(size_t)row * 1024 + tid * 4] = o;
}

// ---------------- launch ----------------
extern "C" void kernel_launch(void* const* d_in, const int* in_sizes, int n_in,
                              void* d_out, int out_size, void* d_ws, size_t ws_size,
                              hipStream_t stream) {
  const float* x     = (const float*)d_in[0];
  const float* Wq    = (const float*)d_in[1];
  const float* bq    = (const float*)d_in[2];
  const float* Wk    = (const float*)d_in[3];
  const float* bk    = (const float*)d_in[4];
  const float* Wv    = (const float*)d_in[5];
  const float* bv    = (const float*)d_in[6];
  const float* Wo    = (const float*)d_in[7];
  const float* bo    = (const float*)d_in[8];
  const float* gamma = (const float*)d_in[9];
  const float* beta  = (const float*)d_in[10];
  float* out = (float*)d_out;

  char* ws = (char*)d_ws;
  u16*   xb  = (u16*)ws;                                   // 8MB  [4096][1024] bf16 (reused as ctx)
  u16*   wb  = (u16*)(ws + (8u << 20));                    // 8MB  Wq|Wk|Wv|Wo bf16
  float* bc  = (float*)(ws + (16u << 20));                 // 12KB bq|bk|bv
  u16*   qkv = (u16*)(ws + (16u << 20) + 16384);           // 24MB Q | K | V^T bf16
  u16*   ctx = xb;                                         // overlay: xb dead after QKV GEMM
  u16*   proj = qkv;                                       // overlay: Q dead after attention

  prep_kernel<<<8195, 256, 0, stream>>>(x, Wq, Wk, Wv, Wo, bq, bk, bv, xb, wb, bc);

  // QKV: M=4096 x N=3072 -> grid 768 (bm=(bid&7)+8*((bid>>3)&3), bn=bid>>5)
  gemm_qkv<<<768, 256, 0, stream>>>(xb, wb, bc, qkv);

  // attention: 512 blocks x 256 threads (4 waves x 32 q), 128 q/block
  attn_kernel<<<512, 256, 0, stream>>>(qkv, qkv + 4194304, qkv + 8388608, ctx);

  // out-proj: M=4096 x N=1024, 64x128 tiles -> grid 512; writes proj bf16 only
  gemm_op<<<512, 256, 0, stream>>>(ctx, wb + 3 * 1048576, bo, proj);

  // LN with fused residual: out = LN(x + proj)
  ln_kernel<<<4096, 256, 0, stream>>>(x, proj, out, gamma, beta);
}

// Round 21
// 121.679 us; speedup vs baseline: 1.2395x; 1.0073x over previous
//
#include <hip/hip_runtime.h>
#include <hip/hip_bf16.h>

// B=4 S=1024 D=1024 H=16 DH=64 -> flat M=4096, attention raw view [64][1024][64]

using u16 = unsigned short;
using u32 = unsigned int;
typedef __attribute__((ext_vector_type(8)))  short bf16x8;
typedef __attribute__((ext_vector_type(4)))  float f32x4;
typedef __attribute__((ext_vector_type(16))) float f32x16;
typedef __attribute__((ext_vector_type(4)))  u16  u16x4;
typedef __attribute__((ext_vector_type(8)))  u16  u16x8;

#define AS1C(p) ((const __attribute__((address_space(1))) void*)(p))
#define AS3(p)  ((__attribute__((address_space(3))) void*)(p))

__device__ __forceinline__ u16 f2bf(float f) {
  union { float f; unsigned u; } v; v.f = f;
  unsigned u = v.u;
  return (u16)((u + 0x7fffu + ((u >> 16) & 1u)) >> 16);  // RNE
}

// one-instruction pack: {lo16 = bf16(a), hi16 = bf16(b)}  (gfx950 v_cvt_pk_bf16_f32, RNE)
__device__ __forceinline__ u32 pk_bf16(float a, float b) {
  u32 r;
  asm("v_cvt_pk_bf16_f32 %0, %1, %2" : "=v"(r) : "v"(a), "v"(b));
  return r;
}
// raw hardware exp2 (v_exp_f32 IS 2^x) — log2e folded into the Q scale upstream
__device__ __forceinline__ float exp2fast(float x) {
  float r;
  asm("v_exp_f32 %0, %1" : "=v"(r) : "v"(x));
  return r;
}
__device__ __forceinline__ float bf2f(u16 b) {
  union { u32 u; float f; } v; v.u = ((u32)b) << 16; return v.f;
}

__device__ __forceinline__ f32x4 mfma16(bf16x8 a, bf16x8 b, f32x4 c) {
  return __builtin_amdgcn_mfma_f32_16x16x32_bf16(a, b, c, 0, 0, 0);
}
__device__ __forceinline__ f32x16 mfma32(bf16x8 a, bf16x8 b, f32x16 c) {
  return __builtin_amdgcn_mfma_f32_32x32x16_bf16(a, b, c, 0, 0, 0);
}

// ---------------- prep: fp32->bf16 for x and W's, concat biases ----------------
__global__ __launch_bounds__(256) void prep_kernel(
    const float* __restrict__ x,
    const float* __restrict__ wq, const float* __restrict__ wk,
    const float* __restrict__ wv, const float* __restrict__ wo,
    const float* __restrict__ bq, const float* __restrict__ bk, const float* __restrict__ bv,
    u16* __restrict__ xb, u16* __restrict__ wb, float* __restrict__ bc)
{
  int ch = blockIdx.x * 256 + threadIdx.x;
  if (ch < 2097152) {
    const float* src; u16* dst;
    if (ch < 1048576) { src = x + ch * 4; dst = xb + ch * 4; }
    else {
      int c2 = ch - 1048576;
      int wsel = c2 >> 18;
      int off  = c2 & 262143;
      const float* wsrc[4] = { wq, wk, wv, wo };
      src = wsrc[wsel] + off * 4;
      dst = wb + wsel * 1048576 + off * 4;
    }
    f32x4 v = *(const f32x4*)src;
    union { u32 u[2]; u16x4 v4; } o;
    o.u[0] = pk_bf16(v[0], v[1]);
    o.u[1] = pk_bf16(v[2], v[3]);
    *(u16x4*)dst = o.v4;
  } else {
    int c3 = ch - 2097152;            // < 768
    int bsel = c3 >> 8, off = c3 & 255;
    const float* bsrc[3] = { bq, bk, bv };
    f32x4 v = *(const f32x4*)(bsrc[bsel] + off * 4);
    *(f32x4*)(bc + bsel * 1024 + off * 4) = v;
  }
}

// ---------------- QKV GEMM: 128x128, BK=32, 4 waves, 3-buf counted vmcnt + setprio ----------------
// r11-proven optimum (57-62us). Per K-step: vmcnt(4) -> s_barrier -> STAGE(t+2) -> COMPUTE(t).
// 48KB LDS -> 3 blocks/CU (12 waves/CU). Design-space sweep (r2..r13): 2-phase drain 63.5,
// 4-buf/2blk 96.5, 8-phase-256^2 87, 8-wave 80.5, no-setprio 105 -> THIS config wins:
//  - s_setprio(1) around MFMA cluster: ESSENTIAL (r9 A/B: removing = 59.5->105.5us)
//  - 16 MFMA/wave/step cluster length: ESSENTIAL (r12: halving = 61->80.5us)
//  - block map keeps all 8 writers of each V^T 128B line on one XCD (r5: else 3x write amp)
// Q scale = 0.125*log2(e) -> attention softmax runs in exp2 domain.
__global__ __launch_bounds__(256) void gemm_qkv(
    const u16* __restrict__ A, const u16* __restrict__ Bw,
    const float* __restrict__ bias, u16* __restrict__ outb)
{
  __shared__ u16 As[3][4096];
  __shared__ u16 Bs[3][4096];

  const int K = 1024;
  int tid = threadIdx.x, w = tid >> 6, lane = tid & 63;
  int g = lane >> 4, lr = lane & 15;
  int wr = w >> 1, wcn = w & 1;

  int bid = blockIdx.x;
  int bm = (bid & 7) + 8 * ((bid >> 3) & 3);
  int bn = bid >> 5;

  int ch0 = tid, ch1 = tid + 256;
  auto srcoff = [&](int ch) -> size_t {
    int r = ch >> 2, pc = ch & 3;
    int gc = pc ^ ((r >> 2) & 3);        // source pre-swizzle (involution)
    return (size_t)r * K + gc * 8;
  };
  const u16* aS0 = A  + (size_t)(bm * 128) * K + srcoff(ch0);
  const u16* aS1 = A  + (size_t)(bm * 128) * K + srcoff(ch1);
  const u16* bS0 = Bw + (size_t)(bn * 128) * K + srcoff(ch0);
  const u16* bS1 = Bw + (size_t)(bn * 128) * K + srcoff(ch1);
  int lo0 = ch0 * 8, lo1 = ch1 * 8;

  auto STAGE = [&](int buf, int kt) {
    __builtin_amdgcn_global_load_lds(AS1C(aS0 + kt * 32), AS3(&As[buf][lo0]), 16, 0, 0);
    __builtin_amdgcn_global_load_lds(AS1C(aS1 + kt * 32), AS3(&As[buf][lo1]), 16, 0, 0);
    __builtin_amdgcn_global_load_lds(AS1C(bS0 + kt * 32), AS3(&Bs[buf][lo0]), 16, 0, 0);
    __builtin_amdgcn_global_load_lds(AS1C(bS1 + kt * 32), AS3(&Bs[buf][lo1]), 16, 0, 0);
  };

  f32x4 acc[4][4] = {};
  int pc8 = (g ^ ((lr >> 2) & 3)) * 8;   // swizzled read chunk

  auto COMPUTE = [&](int buf) {
    bf16x8 af[4], bfr[4];
#pragma unroll
    for (int m = 0; m < 4; ++m)
      af[m] = *(const bf16x8*)&As[buf][(wr * 64 + m * 16 + lr) * 32 + pc8];
#pragma unroll
    for (int n = 0; n < 4; ++n)
      bfr[n] = *(const bf16x8*)&Bs[buf][(wcn * 64 + n * 16 + lr) * 32 + pc8];
    __builtin_amdgcn_s_setprio(1);
#pragma unroll
    for (int m = 0; m < 4; ++m)
#pragma unroll
      for (int n = 0; n < 4; ++n)
        acc[m][n] = mfma16(af[m], bfr[n], acc[m][n]);
    __builtin_amdgcn_s_setprio(0);
  };

  STAGE(0, 0); STAGE(1, 1);

  int sb = 2, cb = 0;
  for (int t = 0; t < 31; ++t) {
    asm volatile("s_waitcnt vmcnt(4)" ::: "memory");  // tile t landed; t+1 in flight
    __builtin_amdgcn_s_barrier();
    asm volatile("" ::: "memory");
    if (t < 30) {
      STAGE(sb, t + 2);
      if (++sb == 3) sb = 0;
    }
    COMPUTE(cb);
    if (++cb == 3) cb = 0;
  }
  asm volatile("s_waitcnt vmcnt(0)" ::: "memory");
  __builtin_amdgcn_s_barrier();
  asm volatile("" ::: "memory");
  COMPUTE(cb);

  // epilogue: D layout col=lane&15, row=(lane>>4)*4+i
#pragma unroll
  for (int m = 0; m < 4; ++m) {
    int row0 = bm * 128 + wr * 64 + m * 16 + 4 * g;
#pragma unroll
    for (int n = 0; n < 4; ++n) {
      int col = bn * 128 + wcn * 64 + n * 16 + lr;
#pragma unroll
      for (int i = 0; i < 4; ++i) {
        float v = acc[m][n][i] + bias[col];
        int r = row0 + i;
        if (col < 1024) {
          outb[(size_t)r * 1024 + col] = f2bf(v * 0.18033688f);           // Q * (1/8)*log2(e)
        } else if (col < 2048) {
          outb[4194304 + (size_t)r * 1024 + (col - 1024)] = f2bf(v);     // K
        } else {
          int c = col - 2048;
          // V^T[bh=r>>6][dh=c&63][k=(r&63)*16+(c>>6)]
          outb[8388608 + (size_t)(r >> 6) * 65536 + (size_t)(c & 63) * 1024
               + (r & 63) * 16 + (c >> 6)] = f2bf(v);
        }
      }
    }
  }
}

// ---------------- out-proj GEMM: 64x128 tile, BK=32, 4 waves, 3-buf counted + setprio ----------------
// Writes proj = ctx*Wo^T + bo as bf16 ONLY (8MB); residual-add lives in ln_kernel (r14: -3us).
__global__ __launch_bounds__(256) void gemm_op(
    const u16* __restrict__ A, const u16* __restrict__ Bw,
    const float* __restrict__ bias, u16* __restrict__ outp)
{
  __shared__ u16 As[3][2048];    // [64][32] per buffer
  __shared__ u16 Bs[3][4096];    // [128][32]

  const int K = 1024;
  int tid = threadIdx.x, w = tid >> 6, lane = tid & 63;
  int g = lane >> 4, lr = lane & 15;
  int wr = w >> 1, wcn = w & 1;
  int bid = blockIdx.x;
  int bm = bid & 63, bn = bid >> 6;      // grid 512 = 64 x 8

  auto srcoff = [&](int ch) -> size_t {
    int r = ch >> 2, pc = ch & 3;
    int gc = pc ^ ((r >> 2) & 3);
    return (size_t)r * K + gc * 8;
  };
  const u16* aS0 = A  + (size_t)(bm * 64)  * K + srcoff(tid);
  const u16* bS0 = Bw + (size_t)(bn * 128) * K + srcoff(tid);
  const u16* bS1 = Bw + (size_t)(bn * 128) * K + srcoff(tid + 256);

  auto STAGE = [&](int buf, int kt) {
    __builtin_amdgcn_global_load_lds(AS1C(aS0 + kt * 32), AS3(&As[buf][tid * 8]),        16, 0, 0);
    __builtin_amdgcn_global_load_lds(AS1C(bS0 + kt * 32), AS3(&Bs[buf][tid * 8]),        16, 0, 0);
    __builtin_amdgcn_global_load_lds(AS1C(bS1 + kt * 32), AS3(&Bs[buf][2048 + tid * 8]), 16, 0, 0);
  };

  f32x4 acc[2][4] = {};
  int pc8 = (g ^ ((lr >> 2) & 3)) * 8;

  auto COMPUTE = [&](int buf) {
    bf16x8 af[2], bfr[4];
#pragma unroll
    for (int m = 0; m < 2; ++m)
      af[m] = *(const bf16x8*)&As[buf][(wr * 32 + m * 16 + lr) * 32 + pc8];
#pragma unroll
    for (int n = 0; n < 4; ++n)
      bfr[n] = *(const bf16x8*)&Bs[buf][(wcn * 64 + n * 16 + lr) * 32 + pc8];
    __builtin_amdgcn_s_setprio(1);
#pragma unroll
    for (int m = 0; m < 2; ++m)
#pragma unroll
      for (int n = 0; n < 4; ++n)
        acc[m][n] = mfma16(af[m], bfr[n], acc[m][n]);
    __builtin_amdgcn_s_setprio(0);
  };

  STAGE(0, 0); STAGE(1, 1);

  int sb = 2, cb = 0;
  for (int t = 0; t < 31; ++t) {
    asm volatile("s_waitcnt vmcnt(3)" ::: "memory");
    __builtin_amdgcn_s_barrier();
    asm volatile("" ::: "memory");
    if (t < 30) {
      STAGE(sb, t + 2);
      if (++sb == 3) sb = 0;
    }
    COMPUTE(cb);
    if (++cb == 3) cb = 0;
  }
  asm volatile("s_waitcnt vmcnt(0)" ::: "memory");
  __builtin_amdgcn_s_barrier();
  asm volatile("" ::: "memory");
  COMPUTE(cb);

#pragma unroll
  for (int m = 0; m < 2; ++m) {
    int row0 = bm * 64 + wr * 32 + m * 16 + 4 * g;
#pragma unroll
    for (int n = 0; n < 4; ++n) {
      int col = bn * 128 + wcn * 64 + n * 16 + lr;
#pragma unroll
      for (int i = 0; i < 4; ++i)
        outp[(size_t)(row0 + i) * 1024 + col] = f2bf(acc[m][n][i] + bias[col]);
    }
  }
}

// ---------------- flash attention, 32x32 swapped-operand + 3-buf counted vmcnt + setprio ----------------
// r14-proven (~30us). __launch_bounds__(256,4): cap VGPR at 128 so 4 waves/SIMD (4 blocks/CU
// with 36KB LDS) is guaranteed — occupancy insurance; live-set estimate ~110 VGPR, no spill.
// LDS staging is the coalescing transformer (r19 lesson: removing it = 75us, VMEM-issue-bound;
// direct fragment loads stride 128B/2KB per lane -> 32-64 lines per load).
// View [64 bh][1024 k][64 d]. 4 waves/block, 32 q/wave (QBLK=128), KV-tile 64, 512 blocks.
// Per tile t: vmcnt(4) -> s_barrier -> STAGE(t+2) -> compute(t); mod-3 buffers, prefetch 2.
//   S^T = mfma32(K,Q): lane owns all 64 S-values of q=lane&31 (Q pre-scaled by (1/8)*log2e
//   -> softmax in exp2 domain: raw v_exp_f32). Defer-max THR=11 (log2) ~ e^8.
//   P pack via v_cvt_pk_bf16_f32; P->PV B-frag via one hi/lo exchange (r8-verified).
__global__ __launch_bounds__(256, 4) void attn_kernel(
    const u16* __restrict__ Qb, const u16* __restrict__ Kb,
    const u16* __restrict__ Vtb, u16* __restrict__ Ob)
{
  __shared__ u16 Ks[3][4096];    // [k_local 64][d 64], 16B-chunk XOR swizzle c^(r&7)
  __shared__ u16 Vts[3][4096];   // [d 64][k_local 64], same swizzle

  int blk = blockIdx.x;
  int bh = blk & 63, qt = blk >> 6;          // head h always on XCD h%8 -> K/V L2-resident
  int tid = threadIdx.x, wid = tid >> 6, lane = tid & 63;
  int l31 = lane & 31, hi = lane >> 5;

  const u16* Qp = Qb  + (size_t)bh * 65536;
  const u16* Kp = Kb  + (size_t)bh * 65536;
  const u16* Vp = Vtb + (size_t)bh * 65536;

  int q = qt * 128 + wid * 32 + l31;

  // Q as B-operand: lane holds Q[q][s*16+hi*8 .. +8] per 16-k step s
  bf16x8 qf[4];
#pragma unroll
  for (int s = 0; s < 4; ++s)
    qf[s] = *(const bf16x8*)&Qp[(size_t)q * 64 + s * 16 + hi * 8];

  f32x16 oacc[2] = {};
  float mrow = -3e38f, lrow = 0.f;

  // staging: 512 chunks of 16B per operand per tile; 256 threads -> 2 chunks each
  const u16* gk[2]; const u16* gv[2];
#pragma unroll
  for (int j = 0; j < 2; ++j) {
    int ch = tid + 256 * j;
    int kc = ch >> 3, scc = ch & 7;
    int sc = scc ^ (kc & 7);                     // pre-swizzled source chunk
    gk[j] = Kp + (size_t)kc * 64   + sc * 8;     // + kt*4096
    gv[j] = Vp + (size_t)kc * 1024 + sc * 8;     // row=dh, + kt*64
  }

  auto STAGE = [&](int buf, int kt) {
#pragma unroll
    for (int j = 0; j < 2; ++j) {
      int ch = tid + 256 * j;
      __builtin_amdgcn_global_load_lds(AS1C(gk[j] + (size_t)kt * 4096), AS3(&Ks[buf][ch * 8]),  16, 0, 0);
      __builtin_amdgcn_global_load_lds(AS1C(gv[j] + kt * 64),           AS3(&Vts[buf][ch * 8]), 16, 0, 0);
    }
  };

  STAGE(0, 0); STAGE(1, 1);

  int sb = 2, cb = 0;
  for (int kt = 0; kt < 16; ++kt) {
    if (kt < 15) { asm volatile("s_waitcnt vmcnt(4)" ::: "memory"); }
    else         { asm volatile("s_waitcnt vmcnt(0)" ::: "memory"); }
    __builtin_amdgcn_s_barrier();
    asm volatile("" ::: "memory");
    if (kt < 14) {
      STAGE(sb, kt + 2);
      if (++sb == 3) sb = 0;
    }

    // --- S^T = K Q^T (log2-domain scores)
    f32x16 s2[2];
#pragma unroll
    for (int ks = 0; ks < 2; ++ks) {
      f32x16 z = {};
      int row = ks * 32 + l31;
      int rx = (row & 7);
      __builtin_amdgcn_s_setprio(1);
#pragma unroll
      for (int s = 0; s < 4; ++s) {
        bf16x8 kb = *(const bf16x8*)&Ks[cb][row * 64 + (((2 * s + hi) ^ rx) * 8)];
        z = mfma32(kb, qf[s], z);
      }
      __builtin_amdgcn_s_setprio(0);
      s2[ks] = z;
    }

    // --- online softmax, in-register (lane owns row q), defer-max THR=11 (log2)
    float tv[16];
#pragma unroll
    for (int r = 0; r < 16; ++r) tv[r] = fmaxf(s2[0][r], s2[1][r]);
#pragma unroll
    for (int st = 8; st > 0; st >>= 1)
#pragma unroll
      for (int r = 0; r < st; ++r) tv[r] = fmaxf(tv[r], tv[r + st]);
    float tm = fmaxf(tv[0], __shfl_xor(tv[0], 32));

    bool nores = __all(tm - mrow <= 11.0f);
    float mn, corr;
    if (nores) { mn = mrow; corr = 1.f; }
    else       { mn = fmaxf(mrow, tm); corr = exp2fast(mrow - mn); }

    float sv[16];
#pragma unroll
    for (int r = 0; r < 16; ++r) {
      s2[0][r] = exp2fast(s2[0][r] - mn);
      s2[1][r] = exp2fast(s2[1][r] - mn);
      sv[r] = s2[0][r] + s2[1][r];
    }
#pragma unroll
    for (int st = 8; st > 0; st >>= 1)
#pragma unroll
      for (int r = 0; r < st; ++r) sv[r] += sv[r + st];
    float rs = sv[0] + __shfl_xor(sv[0], 32);

    if (nores) {
      lrow += rs;
    } else {
#pragma unroll
      for (int dt = 0; dt < 2; ++dt)
#pragma unroll
        for (int r = 0; r < 16; ++r) oacc[dt][r] *= corr;
      lrow = lrow * corr + rs;
      mrow = mn;
    }

    // --- pack P to bf16 pairs via cvt_pk: w[ks][r1][p] = {k=4hi+8r1+2p, +1}
    u32 wpk[2][4][2];
#pragma unroll
    for (int ks = 0; ks < 2; ++ks)
#pragma unroll
      for (int r1 = 0; r1 < 4; ++r1)
#pragma unroll
        for (int p = 0; p < 2; ++p)
          wpk[ks][r1][p] = pk_bf16(s2[ks][4 * r1 + 2 * p], s2[ks][4 * r1 + 2 * p + 1]);

    // --- PV: 4 k-steps of 16; build pb via one hi/lo exchange (r8-verified)
#pragma unroll
    for (int s = 0; s < 4; ++s) {
      int ks = s >> 1, t = s & 1;
      u32 a0 = wpk[ks][2 * t][0],     a1 = wpk[ks][2 * t][1];
      u32 b0 = wpk[ks][2 * t + 1][0], b1 = wpk[ks][2 * t + 1][1];
      u32 sa0 = (u32)__shfl_xor((int)a0, 32), sa1 = (u32)__shfl_xor((int)a1, 32);
      u32 sb0 = (u32)__shfl_xor((int)b0, 32), sb1 = (u32)__shfl_xor((int)b1, 32);
      union { u32 u[4]; bf16x8 v; } pb;
      pb.u[0] = hi ? sb0 : a0;
      pb.u[1] = hi ? sb1 : a1;
      pb.u[2] = hi ? b0 : sa0;
      pb.u[3] = hi ? b1 : sa1;
      __builtin_amdgcn_s_setprio(1);
#pragma unroll
      for (int dt = 0; dt < 2; ++dt) {
        int row = dt * 32 + l31;
        bf16x8 vb = *(const bf16x8*)&Vts[cb][row * 64 + (((2 * s + hi) ^ (row & 7)) * 8)];
        oacc[dt] = mfma32(vb, pb.v, oacc[dt]);
      }
      __builtin_amdgcn_s_setprio(0);
    }

    if (++cb == 3) cb = 0;
  }

  // epilogue: ctx[q][d] = O^T[d][q] / lrow ; d_local(reg r) = (r&3)+8*(r>>2)+4hi
  float inv = 1.f / lrow;
  u16* Op = Ob + (size_t)bh * 65536 + (size_t)q * 64;
#pragma unroll
  for (int dt = 0; dt < 2; ++dt)
#pragma unroll
    for (int rq = 0; rq < 4; ++rq) {
      int d0 = dt * 32 + 8 * rq + 4 * hi;
      union { u32 u[2]; u16x4 v; } o4;
      o4.u[0] = pk_bf16(oacc[dt][4 * rq + 0] * inv, oacc[dt][4 * rq + 1] * inv);
      o4.u[1] = pk_bf16(oacc[dt][4 * rq + 2] * inv, oacc[dt][4 * rq + 3] * inv);
      *(u16x4*)&Op[d0] = o4.v;
    }
}

// ---------------- LayerNorm: out = LN(x + proj), rows of [4096][1024] ----------------
// Residual add fused here (r14): reads proj bf16 (8MB) + x f32 (16MB), writes out f32 (16MB).
__global__ __launch_bounds__(256) void ln_kernel(
    const float* __restrict__ xres, const u16* __restrict__ proj,
    float* __restrict__ out,
    const float* __restrict__ gamma, const float* __restrict__ beta)
{
  int row = blockIdx.x, tid = threadIdx.x;
  int lane = tid & 63, wid = tid >> 6;
  f32x4 xv = *(const f32x4*)&xres[(size_t)row * 1024 + tid * 4];
  u16x4 pv = *(const u16x4*)&proj[(size_t)row * 1024 + tid * 4];
  f32x4 v;
#pragma unroll
  for (int j = 0; j < 4; ++j) v[j] = xv[j] + bf2f(pv[j]);
  float s = v[0] + v[1] + v[2] + v[3];
  float q = v[0] * v[0] + v[1] * v[1] + v[2] * v[2] + v[3] * v[3];
#pragma unroll
  for (int ms = 1; ms < 64; ms <<= 1) { s += __shfl_xor(s, ms); q += __shfl_xor(q, ms); }
  __shared__ float red[8];
  if (lane == 0) { red[wid] = s; red[wid + 4] = q; }
  __syncthreads();
  s = red[0] + red[1] + red[2] + red[3];
  q = red[4] + red[5] + red[6] + red[7];
  float mu = s * (1.f / 1024.f);
  float var = q * (1.f / 1024.f) - mu * mu;
  float inv = rsqrtf(var + 1e-5f);
  f32x4 g4 = *(const f32x4*)&gamma[tid * 4];
  f32x4 b4 = *(const f32x4*)&beta[tid * 4];
  f32x4 o;
#pragma unroll
  for (int j = 0; j < 4; ++j) o[j] = (v[j] - mu) * inv * g4[j] + b4[j];
  *(f32x4*)&out[(size_t)row * 1024 + tid * 4] = o;
}

// ---------------- launch ----------------
extern "C" void kernel_launch(void* const* d_in, const int* in_sizes, int n_in,
                              void* d_out, int out_size, void* d_ws, size_t ws_size,
                              hipStream_t stream) {
  const float* x     = (const float*)d_in[0];
  const float* Wq    = (const float*)d_in[1];
  const float* bq    = (const float*)d_in[2];
  const float* Wk    = (const float*)d_in[3];
  const float* bk    = (const float*)d_in[4];
  const float* Wv    = (const float*)d_in[5];
  const float* bv    = (const float*)d_in[6];
  const float* Wo    = (const float*)d_in[7];
  const float* bo    = (const float*)d_in[8];
  const float* gamma = (const float*)d_in[9];
  const float* beta  = (const float*)d_in[10];
  float* out = (float*)d_out;

  char* ws = (char*)d_ws;
  u16*   xb  = (u16*)ws;                                   // 8MB  [4096][1024] bf16 (reused as ctx)
  u16*   wb  = (u16*)(ws + (8u << 20));                    // 8MB  Wq|Wk|Wv|Wo bf16
  float* bc  = (float*)(ws + (16u << 20));                 // 12KB bq|bk|bv
  u16*   qkv = (u16*)(ws + (16u << 20) + 16384);           // 24MB Q | K | V^T bf16
  u16*   ctx = xb;                                         // overlay: xb dead after QKV GEMM
  u16*   proj = qkv;                                       // overlay: Q dead after attention

  prep_kernel<<<8195, 256, 0, stream>>>(x, Wq, Wk, Wv, Wo, bq, bk, bv, xb, wb, bc);

  // QKV: M=4096 x N=3072 -> grid 768 (bm=(bid&7)+8*((bid>>3)&3), bn=bid>>5)
  gemm_qkv<<<768, 256, 0, stream>>>(xb, wb, bc, qkv);

  // attention: 512 blocks x 256 threads (4 waves x 32 q), 128 q/block
  attn_kernel<<<512, 256, 0, stream>>>(qkv, qkv + 4194304, qkv + 8388608, ctx);

  // out-proj: M=4096 x N=1024, 64x128 tiles -> grid 512; writes proj bf16 only
  gemm_op<<<512, 256, 0, stream>>>(ctx, wb + 3 * 1048576, bo, proj);

  // LN with fused residual: out = LN(x + proj)
  ln_kernel<<<4096, 256, 0, stream>>>(x, proj, out, gamma, beta);
}